// Round 8
// baseline (1262.760 us; speedup 1.0000x reference)
//
#include <hip/hip_runtime.h>
#include <stdint.h>

#define SEQ 32768
#define DIM 1024
#define FFD 4096
#define NE 8
#define CAP 5120

typedef __bf16 bf16x8 __attribute__((ext_vector_type(8)));
typedef float f32x4 __attribute__((ext_vector_type(4)));

__device__ __forceinline__ short f2bf(float f) {
  uint32_t u = __float_as_uint(f);
  uint32_t r = (u + 0x7fffu + ((u >> 16) & 1u)) >> 16;
  return (short)r;
}

__device__ __forceinline__ void async_copy16(const void* g, void* lds) {
  __builtin_amdgcn_global_load_lds((const __attribute__((address_space(1))) void*)g,
                                   (__attribute__((address_space(3))) void*)lds, 16, 0, 0);
}

// tanh-form gelu via __expf/__frcp_rn (verified round 7)
__device__ __forceinline__ float gelu_tanh(float v) {
  float u = v * v;
  float z = v * fmaf(0.07135371f, u, 1.5957691f);
  float E = __expf(z);
  float R = __frcp_rn(1.0f + E);
  return fmaf(-v, R, v);
}

// ---------------- router: logits in f64, argmax + p_max ----------------
__global__ __launch_bounds__(256) void moe_router(const float* __restrict__ x,
                                                  const float* __restrict__ Wg,
                                                  const float* __restrict__ bg,
                                                  int* __restrict__ routes,
                                                  float* __restrict__ pmax) {
  int token = blockIdx.x * 4 + (threadIdx.x >> 6);
  int lane = threadIdx.x & 63;
  const float* xr = x + (size_t)token * DIM;
  double acc[NE];
#pragma unroll
  for (int e = 0; e < NE; e++) acc[e] = 0.0;
#pragma unroll
  for (int i = 0; i < DIM / 64; i++) {
    int d = i * 64 + lane;
    double xv = (double)xr[d];
    const float* wr = Wg + (size_t)d * NE;
    float4 w0 = *(const float4*)(wr);
    float4 w1 = *(const float4*)(wr + 4);
    acc[0] += xv * (double)w0.x; acc[1] += xv * (double)w0.y;
    acc[2] += xv * (double)w0.z; acc[3] += xv * (double)w0.w;
    acc[4] += xv * (double)w1.x; acc[5] += xv * (double)w1.y;
    acc[6] += xv * (double)w1.z; acc[7] += xv * (double)w1.w;
  }
#pragma unroll
  for (int e = 0; e < NE; e++) {
#pragma unroll
    for (int off = 32; off >= 1; off >>= 1) acc[e] += __shfl_xor(acc[e], off);
  }
  if (lane == 0) {
    double l[NE];
#pragma unroll
    for (int e = 0; e < NE; e++) l[e] = acc[e] + (double)bg[e];
    int am = 0;
#pragma unroll
    for (int e = 1; e < NE; e++) if (l[e] > l[am]) am = e;
    double s = 0.0;
#pragma unroll
    for (int e = 0; e < NE; e++) s += exp(l[e] - l[am]);
    routes[token] = am;
    pmax[token] = (float)(1.0 / s);
  }
}

// ---------------- scan: per-expert FCFS positions ----------------
__global__ __launch_bounds__(1024) void moe_scan(const int* __restrict__ routes,
                                                 int* __restrict__ slot_of_token,
                                                 int* __restrict__ token_of_slot,
                                                 int* __restrict__ counts) {
  __shared__ int wtot[16][NE];
  __shared__ int woff[16][NE];
  int t = threadIdx.x, lane = t & 63, w = t >> 6;
  int cnt[NE];
#pragma unroll
  for (int e = 0; e < NE; e++) cnt[e] = 0;
  int base = t * 32;
  for (int i = 0; i < 32; i++) {
    int r = routes[base + i];
#pragma unroll
    for (int e = 0; e < NE; e++) cnt[e] += (r == e) ? 1 : 0;
  }
  int incl[NE];
#pragma unroll
  for (int e = 0; e < NE; e++) {
    int v = cnt[e];
#pragma unroll
    for (int off = 1; off < 64; off <<= 1) {
      int o = __shfl_up(v, off);
      if (lane >= off) v += o;
    }
    incl[e] = v;
    if (lane == 63) wtot[w][e] = v;
  }
  __syncthreads();
  if (t < NE) {
    int run = 0;
    for (int ww = 0; ww < 16; ww++) {
      int tmp = wtot[ww][t];
      woff[ww][t] = run;
      run += tmp;
    }
    counts[t] = run;
  }
  __syncthreads();
  int pos[NE];
#pragma unroll
  for (int e = 0; e < NE; e++) pos[e] = woff[w][e] + incl[e] - cnt[e];
  for (int i = 0; i < 32; i++) {
    int tok = base + i;
    int r = routes[tok];
    int p = 0;
#pragma unroll
    for (int e = 0; e < NE; e++)
      if (r == e) { p = pos[e]; pos[e] = p + 1; }
    bool kept = p < CAP;
    int slot = kept ? r * CAP + p : NE * CAP;
    slot_of_token[tok] = slot;
    if (kept) token_of_slot[slot] = tok;
  }
}

// ---------------- gather dispatch buffer (bf16), zeros for empty slots ----------------
__global__ __launch_bounds__(256) void moe_gather(const float* __restrict__ x,
                                                  const int* __restrict__ token_of_slot,
                                                  short* __restrict__ Xd) {
  int slot = blockIdx.x;
  int tok = token_of_slot[slot];
  int t = threadIdx.x;
  short* dst = Xd + (size_t)slot * DIM + t * 4;
  short4 v;
  if (tok < 0) {
    v.x = 0; v.y = 0; v.z = 0; v.w = 0;
  } else {
    float4 f = *(const float4*)(x + (size_t)tok * DIM + t * 4);
    v.x = f2bf(f.x); v.y = f2bf(f.y); v.z = f2bf(f.z); v.w = f2bf(f.w);
  }
  *(short4*)dst = v;
}

// ---------------- convert f32 [E][K][N] -> bf16 [E][N][K] ----------------
__global__ __launch_bounds__(256) void moe_convT(const float* __restrict__ W,
                                                 short* __restrict__ WT, int K, int N) {
  __shared__ float tile[32][33];
  int e = blockIdx.z;
  const float* We = W + (size_t)e * K * N;
  short* WTe = WT + (size_t)e * K * N;
  int n0 = blockIdx.x * 32, k0 = blockIdx.y * 32;
  int tx = threadIdx.x, ty = threadIdx.y;
#pragma unroll
  for (int i = 0; i < 4; i++)
    tile[ty + i * 8][tx] = We[(size_t)(k0 + ty + i * 8) * N + n0 + tx];
  __syncthreads();
#pragma unroll
  for (int i = 0; i < 4; i++)
    WTe[(size_t)(n0 + ty + i * 8) * K + k0 + tx] = f2bf(tile[tx][ty + i * 8]);
}

// ================= 256x256 8-phase mainloop, A LDS-staged + B reg-loaded =================
// A LDS: buf0 [0,32768)B buf1 [32768,65536)B; halves 16KB each. Swizzle on A only
// (source pre-swizzle + swizzled ds_read, linear gload_lds dest). B-fragments load
// straight from global: wave rows wc*64+nf*16+l15 (nh0) / +32 (nh1), bytes kk*64+kh16
// -- mapping derived from the verified epilogue col-assignment. b0+b1 issued at P1 top
// so L2/L3 latency hides under a-reads + barrier + P1 MFMA.
__device__ __forceinline__ void mainloop256_regB(const short* __restrict__ Ag, int lda,
                                                 const short* __restrict__ Bg, int ldb,
                                                 int NT, short* smem, f32x4 acc[8][4],
                                                 int wr, int wc, int l, int t) {
  const int cb = ((t & 7) << 4) ^ (((t >> 3) & 7) << 4);
  const int rs = t >> 3;
  const size_t la2 = (size_t)lda * 2;
  const char* pa0q0 = (const char*)Ag + (size_t)(rs)       * la2 + cb;
  const char* pa0q1 = (const char*)Ag + (size_t)(128 + rs) * la2 + cb;
  const char* pa1q0 = (const char*)Ag + (size_t)(64 + rs)  * la2 + cb;
  const char* pa1q1 = (const char*)Ag + (size_t)(192 + rs) * la2 + cb;
  short* dA = smem + t * 8;

  auto STG = [&](const char*& p0, const char*& p1, short* d) {
    async_copy16(p0, d);
    async_copy16(p1, d + 4096);
    p0 += 128; p1 += 128;
  };

  // prologue: A(0) h0,h1 then A(1) h0,h1 (8 instr); vmcnt(4) -> A(0) complete
  STG(pa0q0, pa0q1, dA);
  STG(pa1q0, pa1q1, dA + 8192);
  STG(pa0q0, pa0q1, dA + 16384);
  STG(pa1q0, pa1q1, dA + 16384 + 8192);
  asm volatile("s_waitcnt vmcnt(4)" ::: "memory");
  __builtin_amdgcn_s_barrier();

  const int l15 = l & 15;
  const int kh16 = (l >> 4) << 4;
  const int swz = (l15 & 7) << 4;
  const char* paK0 = (const char*)smem + (wr * 64 + l15) * 128 + (kh16 ^ swz);
  const char* paK1 = (const char*)smem + (wr * 64 + l15) * 128 + ((64 + kh16) ^ swz);
  const size_t lb2 = (size_t)ldb * 2;
  const char* pbG = (const char*)Bg + (size_t)(wc * 64 + l15) * lb2 + kh16;
  const size_t nfOff = (size_t)16 * lb2;
  const size_t b1Off = (size_t)32 * lb2;

  for (int T = 0; T < NT; T++) {
    const int selByte = (T & 1) << 15;
    const int selSh = (T & 1) << 14;
    const char* pa0 = paK0 + selByte;
    const char* pa1 = paK1 + selByte;
    bf16x8 a[4][2], b0[2][2], b1[2][2];
    // ---- P1: b0+b1 global (early issue), a half0 LDS
#pragma unroll
    for (int nf = 0; nf < 2; nf++)
#pragma unroll
      for (int kk = 0; kk < 2; kk++) {
        b0[nf][kk] = *(const bf16x8*)(pbG + nf * nfOff + kk * 64);
        b1[nf][kk] = *(const bf16x8*)(pbG + b1Off + nf * nfOff + kk * 64);
      }
#pragma unroll
    for (int mf = 0; mf < 4; mf++) {
      a[mf][0] = *(const bf16x8*)(pa0 + mf * 2048);
      a[mf][1] = *(const bf16x8*)(pa1 + mf * 2048);
    }
    __builtin_amdgcn_s_barrier();
    __builtin_amdgcn_s_setprio(1);
#pragma unroll
    for (int mf = 0; mf < 4; mf++)
#pragma unroll
      for (int nf = 0; nf < 2; nf++)
#pragma unroll
        for (int kk = 0; kk < 2; kk++)
          acc[mf][nf] = __builtin_amdgcn_mfma_f32_16x16x32_bf16(a[mf][kk], b0[nf][kk], acc[mf][nf], 0, 0, 0);
    __builtin_amdgcn_s_setprio(0);
    __builtin_amdgcn_s_barrier();
    // ---- P2: stage A(T+2)h0 -> cur buf half0 (consumed in P1)
    if (T + 2 < NT) STG(pa0q0, pa0q1, dA + selSh);
    __builtin_amdgcn_s_barrier();
    __builtin_amdgcn_s_setprio(1);
#pragma unroll
    for (int mf = 0; mf < 4; mf++)
#pragma unroll
      for (int nf = 0; nf < 2; nf++)
#pragma unroll
        for (int kk = 0; kk < 2; kk++)
          acc[mf][nf + 2] = __builtin_amdgcn_mfma_f32_16x16x32_bf16(a[mf][kk], b1[nf][kk], acc[mf][nf + 2], 0, 0, 0);
    __builtin_amdgcn_s_setprio(0);
    __builtin_amdgcn_s_barrier();
    // ---- P3: a half1 LDS
#pragma unroll
    for (int mf = 0; mf < 4; mf++) {
      a[mf][0] = *(const bf16x8*)(pa0 + 16384 + mf * 2048);
      a[mf][1] = *(const bf16x8*)(pa1 + 16384 + mf * 2048);
    }
    __builtin_amdgcn_s_barrier();
    __builtin_amdgcn_s_setprio(1);
#pragma unroll
    for (int mf = 0; mf < 4; mf++)
#pragma unroll
      for (int nf = 0; nf < 2; nf++)
#pragma unroll
        for (int kk = 0; kk < 2; kk++)
          acc[mf + 4][nf + 2] = __builtin_amdgcn_mfma_f32_16x16x32_bf16(a[mf][kk], b1[nf][kk], acc[mf + 4][nf + 2], 0, 0, 0);
    __builtin_amdgcn_s_setprio(0);
    __builtin_amdgcn_s_barrier();
    // ---- P4: stage A(T+2)h1 -> cur buf half1 (consumed in P3)
    if (T + 2 < NT) STG(pa1q0, pa1q1, dA + 8192 + selSh);
    __builtin_amdgcn_s_barrier();
    __builtin_amdgcn_s_setprio(1);
#pragma unroll
    for (int mf = 0; mf < 4; mf++)
#pragma unroll
      for (int nf = 0; nf < 2; nf++)
#pragma unroll
        for (int kk = 0; kk < 2; kk++)
          acc[mf + 4][nf] = __builtin_amdgcn_mfma_f32_16x16x32_bf16(a[mf][kk], b0[nf][kk], acc[mf + 4][nf], 0, 0, 0);
    __builtin_amdgcn_s_setprio(0);
    // steady state: A(T+1)[4] + A(T+2)[4] outstanding; wait A(T+1) done
    if (T + 2 < NT) asm volatile("s_waitcnt vmcnt(4)" ::: "memory");
    else            asm volatile("s_waitcnt vmcnt(0)" ::: "memory");
    __builtin_amdgcn_s_barrier();
    pbG += 128;
  }
  asm volatile("s_waitcnt vmcnt(0) lgkmcnt(0)" ::: "memory");
  __builtin_amdgcn_s_barrier();
}

// ================= original 256x256 mainloop (A+B LDS) — used by gemm2, verified =====
__device__ __forceinline__ void mainloop256(const short* __restrict__ Ag, int lda,
                                            const short* __restrict__ Bg, int ldb,
                                            int NT, short* smem, f32x4 acc[8][4],
                                            int wr, int wc, int l, int t) {
  const int cb = ((t & 7) << 4) ^ (((t >> 3) & 7) << 4);
  const int rs = t >> 3;
  const int rb = ((rs >> 5) << 6) + (rs & 31);
  const size_t la2 = (size_t)lda * 2, lb2 = (size_t)ldb * 2;
  const char* pa0q0 = (const char*)Ag + (size_t)(rs)       * la2 + cb;
  const char* pa0q1 = (const char*)Ag + (size_t)(128 + rs) * la2 + cb;
  const char* pa1q0 = (const char*)Ag + (size_t)(64 + rs)  * la2 + cb;
  const char* pa1q1 = (const char*)Ag + (size_t)(192 + rs) * la2 + cb;
  const char* pb0q0 = (const char*)Bg + (size_t)(rb)       * lb2 + cb;
  const char* pb0q1 = (const char*)Bg + (size_t)(128 + rb) * lb2 + cb;
  const char* pb1q0 = (const char*)Bg + (size_t)(32 + rb)  * lb2 + cb;
  const char* pb1q1 = (const char*)Bg + (size_t)(160 + rb) * lb2 + cb;
  short* dA = smem + t * 8;
  short* dB = smem + 32768 + t * 8;

  auto STG = [&](const char*& p0, const char*& p1, short* d) {
    async_copy16(p0, d);
    async_copy16(p1, d + 4096);
    p0 += 128; p1 += 128;
  };

  STG(pa0q0, pa0q1, dA);
  STG(pb0q0, pb0q1, dB);
  STG(pa1q0, pa1q1, dA + 8192);
  STG(pb1q0, pb1q1, dB + 8192);
  STG(pa0q0, pa0q1, dA + 16384);
  STG(pb0q0, pb0q1, dB + 16384);
  STG(pa1q0, pa1q1, dA + 16384 + 8192);
  asm volatile("s_waitcnt vmcnt(6)" ::: "memory");
  __builtin_amdgcn_s_barrier();

  const int l15 = l & 15;
  const int kh16 = (l >> 4) << 4;
  const int swz = (l15 & 7) << 4;
  const char* paK0 = (const char*)smem + (wr * 64 + l15) * 128 + (kh16 ^ swz);
  const char* paK1 = (const char*)smem + (wr * 64 + l15) * 128 + ((64 + kh16) ^ swz);
  const char* pbK0 = (const char*)smem + 65536 + (wc * 32 + l15) * 128 + (kh16 ^ swz);
  const char* pbK1 = (const char*)smem + 65536 + (wc * 32 + l15) * 128 + ((64 + kh16) ^ swz);

  for (int T = 0; T < NT; T++) {
    const int selByte = (T & 1) << 15;
    const int selSh = (T & 1) << 14;
    const int selShN = ((T + 1) & 1) << 14;
    const char* pa0 = paK0 + selByte;
    const char* pa1 = paK1 + selByte;
    const char* pb0 = pbK0 + selByte;
    const char* pb1 = pbK1 + selByte;
    bf16x8 a[4][2], b0[2][2], b1[2][2];
#pragma unroll
    for (int mf = 0; mf < 4; mf++) {
      a[mf][0] = *(const bf16x8*)(pa0 + mf * 2048);
      a[mf][1] = *(const bf16x8*)(pa1 + mf * 2048);
    }
#pragma unroll
    for (int nf = 0; nf < 2; nf++) {
      b0[nf][0] = *(const bf16x8*)(pb0 + nf * 2048);
      b0[nf][1] = *(const bf16x8*)(pb1 + nf * 2048);
    }
    if (T + 1 < NT) STG(pb1q0, pb1q1, dB + 8192 + selShN);
    __builtin_amdgcn_s_barrier();
    __builtin_amdgcn_s_setprio(1);
#pragma unroll
    for (int mf = 0; mf < 4; mf++)
#pragma unroll
      for (int nf = 0; nf < 2; nf++)
#pragma unroll
        for (int kk = 0; kk < 2; kk++)
          acc[mf][nf] = __builtin_amdgcn_mfma_f32_16x16x32_bf16(a[mf][kk], b0[nf][kk], acc[mf][nf], 0, 0, 0);
    __builtin_amdgcn_s_setprio(0);
    __builtin_amdgcn_s_barrier();
#pragma unroll
    for (int nf = 0; nf < 2; nf++) {
      b1[nf][0] = *(const bf16x8*)(pb0 + 16384 + nf * 2048);
      b1[nf][1] = *(const bf16x8*)(pb1 + 16384 + nf * 2048);
    }
    if (T + 2 < NT) STG(pa0q0, pa0q1, dA + selSh);
    __builtin_amdgcn_s_barrier();
    __builtin_amdgcn_s_setprio(1);
#pragma unroll
    for (int mf = 0; mf < 4; mf++)
#pragma unroll
      for (int nf = 0; nf < 2; nf++)
#pragma unroll
        for (int kk = 0; kk < 2; kk++)
          acc[mf][nf + 2] = __builtin_amdgcn_mfma_f32_16x16x32_bf16(a[mf][kk], b1[nf][kk], acc[mf][nf + 2], 0, 0, 0);
    __builtin_amdgcn_s_setprio(0);
    __builtin_amdgcn_s_barrier();
#pragma unroll
    for (int mf = 0; mf < 4; mf++) {
      a[mf][0] = *(const bf16x8*)(pa0 + 16384 + mf * 2048);
      a[mf][1] = *(const bf16x8*)(pa1 + 16384 + mf * 2048);
    }
    if (T + 2 < NT) STG(pb0q0, pb0q1, dB + selSh);
    __builtin_amdgcn_s_barrier();
    __builtin_amdgcn_s_setprio(1);
#pragma unroll
    for (int mf = 0; mf < 4; mf++)
#pragma unroll
      for (int nf = 0; nf < 2; nf++)
#pragma unroll
        for (int kk = 0; kk < 2; kk++)
          acc[mf + 4][nf + 2] = __builtin_amdgcn_mfma_f32_16x16x32_bf16(a[mf][kk], b1[nf][kk], acc[mf + 4][nf + 2], 0, 0, 0);
    __builtin_amdgcn_s_setprio(0);
    __builtin_amdgcn_s_barrier();
    if (T + 2 < NT) STG(pa1q0, pa1q1, dA + 8192 + selSh);
    __builtin_amdgcn_s_barrier();
    __builtin_amdgcn_s_setprio(1);
#pragma unroll
    for (int mf = 0; mf < 4; mf++)
#pragma unroll
      for (int nf = 0; nf < 2; nf++)
#pragma unroll
        for (int kk = 0; kk < 2; kk++)
          acc[mf + 4][nf] = __builtin_amdgcn_mfma_f32_16x16x32_bf16(a[mf][kk], b0[nf][kk], acc[mf + 4][nf], 0, 0, 0);
    __builtin_amdgcn_s_setprio(0);
    if (T + 2 < NT) asm volatile("s_waitcnt vmcnt(6)" ::: "memory");
    else            asm volatile("s_waitcnt vmcnt(0)" ::: "memory");
    __builtin_amdgcn_s_barrier();
  }
  asm volatile("s_waitcnt vmcnt(0) lgkmcnt(0)" ::: "memory");
  __builtin_amdgcn_s_barrier();
}

// ---------------- GEMM1: h = gelu(Xd @ W1 + b1), bf16 out (regB mainloop) ------------
#define PITCH1 272  // shorts; 128 x 272 x 2B = 69,632 B (fits 128 KB)
__global__ __launch_bounds__(512, 2) void moe_gemm1(const short* __restrict__ Xd,
                                                    const short* __restrict__ W1bT,
                                                    const float* __restrict__ b1,
                                                    short* __restrict__ h,
                                                    const int* __restrict__ counts,
                                                    int m_base, int rows, int mch) {
  extern __shared__ short smem[];
  int bid = blockIdx.x;
  int xcd = bid & 7;
  int idx = bid >> 3;
  int nn = idx & 15;
  int mlin = (idx >> 4) * 8 + xcd;
  int e = mlin / mch;
  int mm = mlin - e * mch;
  int cnt = counts[e]; if (cnt > CAP) cnt = CAP;
  int m0 = m_base + mm * 256;
  if (m0 >= cnt) return;
  int n0 = nn * 256;
  int t = threadIdx.x, l = t & 63, wid = t >> 6;
  int wr = wid >> 2, wc = wid & 3;
  const short* Ag = Xd + ((size_t)e * CAP + m0) * DIM;
  const short* Bg = W1bT + ((size_t)e * FFD + n0) * DIM;
  f32x4 acc[8][4];
#pragma unroll
  for (int mf = 0; mf < 8; mf++)
#pragma unroll
    for (int nf = 0; nf < 4; nf++) acc[mf][nf] = (f32x4){0.f, 0.f, 0.f, 0.f};
  mainloop256_regB(Ag, DIM, Bg, DIM, DIM / 64, smem, acc, wr, wc, l, t);

  int l15 = l & 15, q4 = (l >> 4) * 4;
  float bias[4];
#pragma unroll
  for (int nf = 0; nf < 4; nf++)
    bias[nf] = b1[(size_t)e * FFD + n0 + wc * 64 + nf * 16 + l15];
#pragma unroll
  for (int half = 0; half < 2; half++) {
    if (wr == half) {
#pragma unroll
      for (int mf = 0; mf < 8; mf++)
#pragma unroll
        for (int nf = 0; nf < 4; nf++)
#pragma unroll
          for (int j = 0; j < 4; j++) {
            int lr = mf * 16 + q4 + j;
            int lc = wc * 64 + nf * 16 + l15;
            float v = acc[mf][nf][j] + bias[nf];
            smem[lr * PITCH1 + lc] = f2bf(gelu_tanh(v));
          }
    }
    asm volatile("s_waitcnt lgkmcnt(0)" ::: "memory");
    __builtin_amdgcn_s_barrier();
    int r = t >> 2, c0 = (t & 3) * 64;
    short* hrow = h + ((size_t)e * rows + (m0 - m_base) + half * 128 + r) * FFD + n0 + c0;
    const short* srow = smem + r * PITCH1 + c0;
#pragma unroll
    for (int i = 0; i < 8; i++)
      *(int4*)(hrow + i * 8) = *(const int4*)(srow + i * 8);
    asm volatile("s_waitcnt lgkmcnt(0)" ::: "memory");
    __builtin_amdgcn_s_barrier();
  }
}

// ---------------- GEMM2: out[token] = (h @ W2 + b2) * p_max, scatter (verified) ------
__global__ __launch_bounds__(512, 2) void moe_gemm2(const short* __restrict__ h,
                                                    const short* __restrict__ W2bT,
                                                    const float* __restrict__ b2,
                                                    const int* __restrict__ token_of_slot,
                                                    const float* __restrict__ pmax,
                                                    float* __restrict__ out,
                                                    const int* __restrict__ counts,
                                                    int m_base, int rows, int mch) {
  extern __shared__ short smem[];
  int bid = blockIdx.x;
  int xcd = bid & 7;
  int idx = bid >> 3;
  int nn = idx & 3;
  int mlin = (idx >> 2) * 8 + xcd;
  int e = mlin / mch;
  int mm = mlin - e * mch;
  int cnt = counts[e]; if (cnt > CAP) cnt = CAP;
  int m0 = m_base + mm * 256;
  if (m0 >= cnt) return;
  int n0 = nn * 256;
  int t = threadIdx.x, l = t & 63, wid = t >> 6;
  int wr = wid >> 2, wc = wid & 3;
  const short* Ag = h + ((size_t)e * rows + (m0 - m_base)) * FFD;
  const short* Bg = W2bT + ((size_t)e * DIM + n0) * FFD;
  f32x4 acc[8][4];
#pragma unroll
  for (int mf = 0; mf < 8; mf++)
#pragma unroll
    for (int nf = 0; nf < 4; nf++) acc[mf][nf] = (f32x4){0.f, 0.f, 0.f, 0.f};
  mainloop256(Ag, FFD, Bg, FFD, FFD / 64, smem, acc, wr, wc, l, t);

  float* ftile = (float*)smem;  // 128 x 256 f32 = 128 KB
  int l15 = l & 15, q4 = (l >> 4) * 4;
  float bias[4];
#pragma unroll
  for (int nf = 0; nf < 4; nf++)
    bias[nf] = b2[(size_t)e * DIM + n0 + wc * 64 + nf * 16 + l15];
#pragma unroll
  for (int half = 0; half < 2; half++) {
    if (wr == half) {
#pragma unroll
      for (int mf = 0; mf < 8; mf++)
#pragma unroll
        for (int nf = 0; nf < 4; nf++)
#pragma unroll
          for (int j = 0; j < 4; j++) {
            int lr = mf * 16 + q4 + j;
            int lc = wc * 64 + nf * 16 + l15;
            ftile[lr * 256 + lc] = acc[mf][nf][j] + bias[nf];
          }
    }
    asm volatile("s_waitcnt lgkmcnt(0)" ::: "memory");
    __builtin_amdgcn_s_barrier();
    int r = t >> 2, c0 = (t & 3) * 64;
    int slotrow = m0 + half * 128 + r;
    int tok = token_of_slot[e * CAP + slotrow];
    if (tok >= 0) {
      float f = pmax[tok];
      float* orow = out + (size_t)tok * DIM + n0 + c0;
      const float* srow = ftile + r * 256 + c0;
#pragma unroll
      for (int i = 0; i < 16; i++) {
        float4 v = *(const float4*)(srow + i * 4);
        v.x *= f; v.y *= f; v.z *= f; v.w *= f;
        *(float4*)(orow + i * 4) = v;
      }
    }
    asm volatile("s_waitcnt lgkmcnt(0)" ::: "memory");
    __builtin_amdgcn_s_barrier();
  }
}

// ---------------- dropped tokens: passthrough x ----------------
__global__ __launch_bounds__(256) void moe_fixup(const float* __restrict__ x,
                                                 const int* __restrict__ slot_of_token,
                                                 float* __restrict__ out) {
  int tok8 = blockIdx.x * 8 + (threadIdx.x >> 5);
  int lane32 = threadIdx.x & 31;
  if (slot_of_token[tok8] != NE * CAP) return;
#pragma unroll
  for (int i = 0; i < 8; i++) {
    int c = (i * 32 + lane32) * 4;
    float4 v = *(const float4*)(x + (size_t)tok8 * DIM + c);
    *(float4*)(out + (size_t)tok8 * DIM + c) = v;
  }
}

extern "C" void kernel_launch(void* const* d_in, const int* in_sizes, int n_in,
                              void* d_out, int out_size, void* d_ws, size_t ws_size,
                              hipStream_t stream) {
  (void)in_sizes; (void)n_in; (void)out_size;
  const float* x  = (const float*)d_in[0];
  const float* Wg = (const float*)d_in[1];
  const float* bg = (const float*)d_in[2];
  const float* W1 = (const float*)d_in[3];
  const float* b1 = (const float*)d_in[4];
  const float* W2 = (const float*)d_in[5];
  const float* b2 = (const float*)d_in[6];
  float* out = (float*)d_out;

  static bool attr_set = false;
  if (!attr_set) {
    hipFuncSetAttribute((const void*)moe_gemm1, hipFuncAttributeMaxDynamicSharedMemorySize, 131072);
    hipFuncSetAttribute((const void*)moe_gemm2, hipFuncAttributeMaxDynamicSharedMemorySize, 131072);
    attr_set = true;
  }

  char* p = (char*)d_ws;
  auto carve = [&](size_t bytes) -> char* {
    char* r = p;
    p += (bytes + 255) & ~(size_t)255;
    return r;
  };
  short* W1bT = (short*)carve((size_t)NE * DIM * FFD * 2);
  short* W2bT = (short*)carve((size_t)NE * DIM * FFD * 2);
  short* Xd   = (short*)carve((size_t)NE * CAP * DIM * 2);
  int* routes = (int*)carve((size_t)SEQ * 4);
  float* pmax = (float*)carve((size_t)SEQ * 4);
  int* slot_of_token = (int*)carve((size_t)SEQ * 4);
  int* token_of_slot = (int*)carve((size_t)(NE * CAP) * 4);
  int* counts = (int*)carve(256);
  size_t fixed = (size_t)(p - (char*)d_ws);

  size_t avail = (ws_size > fixed + 4096) ? (ws_size - fixed - 4096) : 0;
  size_t per_row = (size_t)NE * FFD * 2;
  int rows = (int)(avail / per_row);
  rows &= ~255;
  if (rows > CAP) rows = CAP;
  if (rows < 256) rows = 256;
  short* h = (short*)p;

  hipMemsetAsync(token_of_slot, 0xFF, (size_t)(NE * CAP) * 4, stream);
  moe_router<<<SEQ / 4, 256, 0, stream>>>(x, Wg, bg, routes, pmax);
  moe_scan<<<1, 1024, 0, stream>>>(routes, slot_of_token, token_of_slot, counts);
  moe_gather<<<NE * CAP, 256, 0, stream>>>(x, token_of_slot, Xd);
  moe_convT<<<dim3(FFD / 32, DIM / 32, NE), dim3(32, 8), 0, stream>>>(W1, W1bT, DIM, FFD);
  moe_convT<<<dim3(DIM / 32, FFD / 32, NE), dim3(32, 8), 0, stream>>>(W2, W2bT, FFD, DIM);

  for (int r0 = 0; r0 < CAP; r0 += rows) {
    int cr = (CAP - r0 < rows) ? (CAP - r0) : rows;
    int mch = cr / 256;
    moe_gemm1<<<16 * NE * mch, 512, 131072, stream>>>(Xd, W1bT, b1, h, counts, r0, rows, mch);
    moe_gemm2<<<4 * NE * mch, 512, 131072, stream>>>(h, W2bT, b2, token_of_slot, pmax, out,
                                                     counts, r0, rows, mch);
  }
  moe_fixup<<<SEQ / 8, 256, 0, stream>>>(x, slot_of_token, out);
}

// Round 9
// 1049.760 us; speedup vs baseline: 1.2029x; 1.2029x over previous
//
#include <hip/hip_runtime.h>
#include <stdint.h>

#define SEQ 32768
#define DIM 1024
#define FFD 4096
#define NE 8
#define CAP 5120

typedef __bf16 bf16x8 __attribute__((ext_vector_type(8)));
typedef float f32x4 __attribute__((ext_vector_type(4)));

__device__ __forceinline__ short f2bf(float f) {
  uint32_t u = __float_as_uint(f);
  uint32_t r = (u + 0x7fffu + ((u >> 16) & 1u)) >> 16;
  return (short)r;
}

__device__ __forceinline__ void async_copy16(const void* g, void* lds) {
  __builtin_amdgcn_global_load_lds((const __attribute__((address_space(1))) void*)g,
                                   (__attribute__((address_space(3))) void*)lds, 16, 0, 0);
}

// tanh-form gelu via __expf/__frcp_rn (verified round 7)
__device__ __forceinline__ float gelu_tanh(float v) {
  float u = v * v;
  float z = v * fmaf(0.07135371f, u, 1.5957691f);
  float E = __expf(z);
  float R = __frcp_rn(1.0f + E);
  return fmaf(-v, R, v);
}

// ---------------- router: logits in f64, argmax + p_max ----------------
__global__ __launch_bounds__(256) void moe_router(const float* __restrict__ x,
                                                  const float* __restrict__ Wg,
                                                  const float* __restrict__ bg,
                                                  int* __restrict__ routes,
                                                  float* __restrict__ pmax) {
  int token = blockIdx.x * 4 + (threadIdx.x >> 6);
  int lane = threadIdx.x & 63;
  const float* xr = x + (size_t)token * DIM;
  double acc[NE];
#pragma unroll
  for (int e = 0; e < NE; e++) acc[e] = 0.0;
#pragma unroll
  for (int i = 0; i < DIM / 64; i++) {
    int d = i * 64 + lane;
    double xv = (double)xr[d];
    const float* wr = Wg + (size_t)d * NE;
    float4 w0 = *(const float4*)(wr);
    float4 w1 = *(const float4*)(wr + 4);
    acc[0] += xv * (double)w0.x; acc[1] += xv * (double)w0.y;
    acc[2] += xv * (double)w0.z; acc[3] += xv * (double)w0.w;
    acc[4] += xv * (double)w1.x; acc[5] += xv * (double)w1.y;
    acc[6] += xv * (double)w1.z; acc[7] += xv * (double)w1.w;
  }
#pragma unroll
  for (int e = 0; e < NE; e++) {
#pragma unroll
    for (int off = 32; off >= 1; off >>= 1) acc[e] += __shfl_xor(acc[e], off);
  }
  if (lane == 0) {
    double l[NE];
#pragma unroll
    for (int e = 0; e < NE; e++) l[e] = acc[e] + (double)bg[e];
    int am = 0;
#pragma unroll
    for (int e = 1; e < NE; e++) if (l[e] > l[am]) am = e;
    double s = 0.0;
#pragma unroll
    for (int e = 0; e < NE; e++) s += exp(l[e] - l[am]);
    routes[token] = am;
    pmax[token] = (float)(1.0 / s);
  }
}

// ---------------- scan: per-expert FCFS positions ----------------
__global__ __launch_bounds__(1024) void moe_scan(const int* __restrict__ routes,
                                                 int* __restrict__ slot_of_token,
                                                 int* __restrict__ token_of_slot,
                                                 int* __restrict__ counts) {
  __shared__ int wtot[16][NE];
  __shared__ int woff[16][NE];
  int t = threadIdx.x, lane = t & 63, w = t >> 6;
  int cnt[NE];
#pragma unroll
  for (int e = 0; e < NE; e++) cnt[e] = 0;
  int base = t * 32;
  for (int i = 0; i < 32; i++) {
    int r = routes[base + i];
#pragma unroll
    for (int e = 0; e < NE; e++) cnt[e] += (r == e) ? 1 : 0;
  }
  int incl[NE];
#pragma unroll
  for (int e = 0; e < NE; e++) {
    int v = cnt[e];
#pragma unroll
    for (int off = 1; off < 64; off <<= 1) {
      int o = __shfl_up(v, off);
      if (lane >= off) v += o;
    }
    incl[e] = v;
    if (lane == 63) wtot[w][e] = v;
  }
  __syncthreads();
  if (t < NE) {
    int run = 0;
    for (int ww = 0; ww < 16; ww++) {
      int tmp = wtot[ww][t];
      woff[ww][t] = run;
      run += tmp;
    }
    counts[t] = run;
  }
  __syncthreads();
  int pos[NE];
#pragma unroll
  for (int e = 0; e < NE; e++) pos[e] = woff[w][e] + incl[e] - cnt[e];
  for (int i = 0; i < 32; i++) {
    int tok = base + i;
    int r = routes[tok];
    int p = 0;
#pragma unroll
    for (int e = 0; e < NE; e++)
      if (r == e) { p = pos[e]; pos[e] = p + 1; }
    bool kept = p < CAP;
    int slot = kept ? r * CAP + p : NE * CAP;
    slot_of_token[tok] = slot;
    if (kept) token_of_slot[slot] = tok;
  }
}

// ---------------- gather dispatch buffer (bf16), zeros for empty slots ----------------
__global__ __launch_bounds__(256) void moe_gather(const float* __restrict__ x,
                                                  const int* __restrict__ token_of_slot,
                                                  short* __restrict__ Xd) {
  int slot = blockIdx.x;
  int tok = token_of_slot[slot];
  int t = threadIdx.x;
  short* dst = Xd + (size_t)slot * DIM + t * 4;
  short4 v;
  if (tok < 0) {
    v.x = 0; v.y = 0; v.z = 0; v.w = 0;
  } else {
    float4 f = *(const float4*)(x + (size_t)tok * DIM + t * 4);
    v.x = f2bf(f.x); v.y = f2bf(f.y); v.z = f2bf(f.z); v.w = f2bf(f.w);
  }
  *(short4*)dst = v;
}

// ---------------- convert f32 [E][K][N] -> bf16 [E][N][K] ----------------
__global__ __launch_bounds__(256) void moe_convT(const float* __restrict__ W,
                                                 short* __restrict__ WT, int K, int N) {
  __shared__ float tile[32][33];
  int e = blockIdx.z;
  const float* We = W + (size_t)e * K * N;
  short* WTe = WT + (size_t)e * K * N;
  int n0 = blockIdx.x * 32, k0 = blockIdx.y * 32;
  int tx = threadIdx.x, ty = threadIdx.y;
#pragma unroll
  for (int i = 0; i < 4; i++)
    tile[ty + i * 8][tx] = We[(size_t)(k0 + ty + i * 8) * N + n0 + tx];
  __syncthreads();
#pragma unroll
  for (int i = 0; i < 4; i++)
    WTe[(size_t)(n0 + ty + i * 8) * K + k0 + tx] = f2bf(tile[tx][ty + i * 8]);
}

// ================= 256x256 8-phase GEMM mainloop (A+B LDS, verified r4-r7) =============
// LDS bytes: A buf0 [0,32768) A buf1 [32768,65536) B buf0 [65536,98304) B buf1 [98304,131072)
// Swizzle: kbyte ^= (lrow&7)<<4 on global SOURCE (pre-swizzle) and on ds_read;
// gload_lds dest stays linear (rule #21).
__device__ __forceinline__ void mainloop256(const short* __restrict__ Ag, int lda,
                                            const short* __restrict__ Bg, int ldb,
                                            int NT, short* smem, f32x4 acc[8][4],
                                            int wr, int wc, int l, int t) {
  const int cb = ((t & 7) << 4) ^ (((t >> 3) & 7) << 4);
  const int rs = t >> 3;
  const int rb = ((rs >> 5) << 6) + (rs & 31);
  const size_t la2 = (size_t)lda * 2, lb2 = (size_t)ldb * 2;
  const char* pa0q0 = (const char*)Ag + (size_t)(rs)       * la2 + cb;
  const char* pa0q1 = (const char*)Ag + (size_t)(128 + rs) * la2 + cb;
  const char* pa1q0 = (const char*)Ag + (size_t)(64 + rs)  * la2 + cb;
  const char* pa1q1 = (const char*)Ag + (size_t)(192 + rs) * la2 + cb;
  const char* pb0q0 = (const char*)Bg + (size_t)(rb)       * lb2 + cb;
  const char* pb0q1 = (const char*)Bg + (size_t)(128 + rb) * lb2 + cb;
  const char* pb1q0 = (const char*)Bg + (size_t)(32 + rb)  * lb2 + cb;
  const char* pb1q1 = (const char*)Bg + (size_t)(160 + rb) * lb2 + cb;
  short* dA = smem + t * 8;
  short* dB = smem + 32768 + t * 8;

  auto STG = [&](const char*& p0, const char*& p1, short* d) {
    async_copy16(p0, d);
    async_copy16(p1, d + 4096);
    p0 += 128; p1 += 128;
  };

  STG(pa0q0, pa0q1, dA);
  STG(pb0q0, pb0q1, dB);
  STG(pa1q0, pa1q1, dA + 8192);
  STG(pb1q0, pb1q1, dB + 8192);
  STG(pa0q0, pa0q1, dA + 16384);
  STG(pb0q0, pb0q1, dB + 16384);
  STG(pa1q0, pa1q1, dA + 16384 + 8192);
  asm volatile("s_waitcnt vmcnt(6)" ::: "memory");
  __builtin_amdgcn_s_barrier();

  const int l15 = l & 15;
  const int kh16 = (l >> 4) << 4;
  const int swz = (l15 & 7) << 4;
  const char* paK0 = (const char*)smem + (wr * 64 + l15) * 128 + (kh16 ^ swz);
  const char* paK1 = (const char*)smem + (wr * 64 + l15) * 128 + ((64 + kh16) ^ swz);
  const char* pbK0 = (const char*)smem + 65536 + (wc * 32 + l15) * 128 + (kh16 ^ swz);
  const char* pbK1 = (const char*)smem + 65536 + (wc * 32 + l15) * 128 + ((64 + kh16) ^ swz);

  for (int T = 0; T < NT; T++) {
    const int selByte = (T & 1) << 15;
    const int selSh = (T & 1) << 14;
    const int selShN = ((T + 1) & 1) << 14;
    const char* pa0 = paK0 + selByte;
    const char* pa1 = paK1 + selByte;
    const char* pb0 = pbK0 + selByte;
    const char* pb1 = pbK1 + selByte;
    bf16x8 a[4][2], b0[2][2], b1[2][2];
#pragma unroll
    for (int mf = 0; mf < 4; mf++) {
      a[mf][0] = *(const bf16x8*)(pa0 + mf * 2048);
      a[mf][1] = *(const bf16x8*)(pa1 + mf * 2048);
    }
#pragma unroll
    for (int nf = 0; nf < 2; nf++) {
      b0[nf][0] = *(const bf16x8*)(pb0 + nf * 2048);
      b0[nf][1] = *(const bf16x8*)(pb1 + nf * 2048);
    }
    if (T + 1 < NT) STG(pb1q0, pb1q1, dB + 8192 + selShN);
    __builtin_amdgcn_s_barrier();
    __builtin_amdgcn_s_setprio(1);
#pragma unroll
    for (int mf = 0; mf < 4; mf++)
#pragma unroll
      for (int nf = 0; nf < 2; nf++)
#pragma unroll
        for (int kk = 0; kk < 2; kk++)
          acc[mf][nf] = __builtin_amdgcn_mfma_f32_16x16x32_bf16(a[mf][kk], b0[nf][kk], acc[mf][nf], 0, 0, 0);
    __builtin_amdgcn_s_setprio(0);
    __builtin_amdgcn_s_barrier();
#pragma unroll
    for (int nf = 0; nf < 2; nf++) {
      b1[nf][0] = *(const bf16x8*)(pb0 + 16384 + nf * 2048);
      b1[nf][1] = *(const bf16x8*)(pb1 + 16384 + nf * 2048);
    }
    if (T + 2 < NT) STG(pa0q0, pa0q1, dA + selSh);
    __builtin_amdgcn_s_barrier();
    __builtin_amdgcn_s_setprio(1);
#pragma unroll
    for (int mf = 0; mf < 4; mf++)
#pragma unroll
      for (int nf = 0; nf < 2; nf++)
#pragma unroll
        for (int kk = 0; kk < 2; kk++)
          acc[mf][nf + 2] = __builtin_amdgcn_mfma_f32_16x16x32_bf16(a[mf][kk], b1[nf][kk], acc[mf][nf + 2], 0, 0, 0);
    __builtin_amdgcn_s_setprio(0);
    __builtin_amdgcn_s_barrier();
#pragma unroll
    for (int mf = 0; mf < 4; mf++) {
      a[mf][0] = *(const bf16x8*)(pa0 + 16384 + mf * 2048);
      a[mf][1] = *(const bf16x8*)(pa1 + 16384 + mf * 2048);
    }
    if (T + 2 < NT) STG(pb0q0, pb0q1, dB + selSh);
    __builtin_amdgcn_s_barrier();
    __builtin_amdgcn_s_setprio(1);
#pragma unroll
    for (int mf = 0; mf < 4; mf++)
#pragma unroll
      for (int nf = 0; nf < 2; nf++)
#pragma unroll
        for (int kk = 0; kk < 2; kk++)
          acc[mf + 4][nf + 2] = __builtin_amdgcn_mfma_f32_16x16x32_bf16(a[mf][kk], b1[nf][kk], acc[mf + 4][nf + 2], 0, 0, 0);
    __builtin_amdgcn_s_setprio(0);
    __builtin_amdgcn_s_barrier();
    if (T + 2 < NT) STG(pa1q0, pa1q1, dA + 8192 + selSh);
    __builtin_amdgcn_s_barrier();
    __builtin_amdgcn_s_setprio(1);
#pragma unroll
    for (int mf = 0; mf < 4; mf++)
#pragma unroll
      for (int nf = 0; nf < 2; nf++)
#pragma unroll
        for (int kk = 0; kk < 2; kk++)
          acc[mf + 4][nf] = __builtin_amdgcn_mfma_f32_16x16x32_bf16(a[mf][kk], b0[nf][kk], acc[mf + 4][nf], 0, 0, 0);
    __builtin_amdgcn_s_setprio(0);
    if (T + 2 < NT) asm volatile("s_waitcnt vmcnt(6)" ::: "memory");
    else            asm volatile("s_waitcnt vmcnt(0)" ::: "memory");
    __builtin_amdgcn_s_barrier();
  }
  asm volatile("s_waitcnt vmcnt(0) lgkmcnt(0)" ::: "memory");
  __builtin_amdgcn_s_barrier();
}

// ---------------- GEMM1: h = gelu(Xd @ W1 + b1), bf16 out ----------------
// L2-window grid decode: each XCD runs 32-block windows (4 M-slabs x 8 N-blocks,
// A 2MB + B 4MB footprint ~= L2); windows col-major so the B-set persists per XCD.
// Requires mch % 4 == 0 (launcher clamps rows to multiples of 1024).
#define PITCH1 272  // shorts; 128 x 272 x 2B = 69,632 B (fits 128 KB)
__global__ __launch_bounds__(512, 2) void moe_gemm1(const short* __restrict__ Xd,
                                                    const short* __restrict__ W1bT,
                                                    const float* __restrict__ b1,
                                                    short* __restrict__ h,
                                                    const int* __restrict__ counts,
                                                    int m_base, int rows, int mch) {
  extern __shared__ short smem[];
  int bid = blockIdx.x;
  int xcd = bid & 7;
  int k = bid >> 3;           // 0 .. 2*NE*mch-1 (per-XCD sequence)
  int sub = k & 31;           // position in 4Mx8N window
  int win = k >> 5;           // per-XCD window index
  int Wm = NE * mch / 4;      // M-windows
  int g = win * 8 + xcd;      // global window id, col-major (wm fast, wn slow)
  int wm = g % Wm;
  int wn = g / Wm;            // 0 or 1
  int mlin = wm * 4 + (sub >> 3);
  int nn = wn * 8 + (sub & 7);
  int e = mlin / mch;
  int mm = mlin - e * mch;
  int cnt = counts[e]; if (cnt > CAP) cnt = CAP;
  int m0 = m_base + mm * 256;
  if (m0 >= cnt) return;
  int n0 = nn * 256;
  int t = threadIdx.x, l = t & 63, wid = t >> 6;
  int wr = wid >> 2, wc = wid & 3;
  const short* Ag = Xd + ((size_t)e * CAP + m0) * DIM;
  const short* Bg = W1bT + ((size_t)e * FFD + n0) * DIM;
  f32x4 acc[8][4];
#pragma unroll
  for (int mf = 0; mf < 8; mf++)
#pragma unroll
    for (int nf = 0; nf < 4; nf++) acc[mf][nf] = (f32x4){0.f, 0.f, 0.f, 0.f};
  mainloop256(Ag, DIM, Bg, DIM, DIM / 64, smem, acc, wr, wc, l, t);

  int l15 = l & 15, q4 = (l >> 4) * 4;
  float bias[4];
#pragma unroll
  for (int nf = 0; nf < 4; nf++)
    bias[nf] = b1[(size_t)e * FFD + n0 + wc * 64 + nf * 16 + l15];
#pragma unroll
  for (int half = 0; half < 2; half++) {
    if (wr == half) {
#pragma unroll
      for (int mf = 0; mf < 8; mf++)
#pragma unroll
        for (int nf = 0; nf < 4; nf++)
#pragma unroll
          for (int j = 0; j < 4; j++) {
            int lr = mf * 16 + q4 + j;
            int lc = wc * 64 + nf * 16 + l15;
            float v = acc[mf][nf][j] + bias[nf];
            smem[lr * PITCH1 + lc] = f2bf(gelu_tanh(v));
          }
    }
    asm volatile("s_waitcnt lgkmcnt(0)" ::: "memory");
    __builtin_amdgcn_s_barrier();
    int r = t >> 2, c0 = (t & 3) * 64;
    short* hrow = h + ((size_t)e * rows + (m0 - m_base) + half * 128 + r) * FFD + n0 + c0;
    const short* srow = smem + r * PITCH1 + c0;
#pragma unroll
    for (int i = 0; i < 8; i++)
      *(int4*)(hrow + i * 8) = *(const int4*)(srow + i * 8);
    asm volatile("s_waitcnt lgkmcnt(0)" ::: "memory");
    __builtin_amdgcn_s_barrier();
  }
}

// ---------------- GEMM2: out[token] = (h @ W2 + b2) * p_max, scatter (verified) ------
__global__ __launch_bounds__(512, 2) void moe_gemm2(const short* __restrict__ h,
                                                    const short* __restrict__ W2bT,
                                                    const float* __restrict__ b2,
                                                    const int* __restrict__ token_of_slot,
                                                    const float* __restrict__ pmax,
                                                    float* __restrict__ out,
                                                    const int* __restrict__ counts,
                                                    int m_base, int rows, int mch) {
  extern __shared__ short smem[];
  int bid = blockIdx.x;
  int xcd = bid & 7;
  int idx = bid >> 3;
  int nn = idx & 3;
  int mlin = (idx >> 2) * 8 + xcd;
  int e = mlin / mch;
  int mm = mlin - e * mch;
  int cnt = counts[e]; if (cnt > CAP) cnt = CAP;
  int m0 = m_base + mm * 256;
  if (m0 >= cnt) return;
  int n0 = nn * 256;
  int t = threadIdx.x, l = t & 63, wid = t >> 6;
  int wr = wid >> 2, wc = wid & 3;
  const short* Ag = h + ((size_t)e * rows + (m0 - m_base)) * FFD;
  const short* Bg = W2bT + ((size_t)e * DIM + n0) * FFD;
  f32x4 acc[8][4];
#pragma unroll
  for (int mf = 0; mf < 8; mf++)
#pragma unroll
    for (int nf = 0; nf < 4; nf++) acc[mf][nf] = (f32x4){0.f, 0.f, 0.f, 0.f};
  mainloop256(Ag, FFD, Bg, FFD, FFD / 64, smem, acc, wr, wc, l, t);

  float* ftile = (float*)smem;  // 128 x 256 f32 = 128 KB (exact fit)
  int l15 = l & 15, q4 = (l >> 4) * 4;
  float bias[4];
#pragma unroll
  for (int nf = 0; nf < 4; nf++)
    bias[nf] = b2[(size_t)e * DIM + n0 + wc * 64 + nf * 16 + l15];
#pragma unroll
  for (int half = 0; half < 2; half++) {
    if (wr == half) {
#pragma unroll
      for (int mf = 0; mf < 8; mf++)
#pragma unroll
        for (int nf = 0; nf < 4; nf++)
#pragma unroll
          for (int j = 0; j < 4; j++) {
            int lr = mf * 16 + q4 + j;
            int lc = wc * 64 + nf * 16 + l15;
            ftile[lr * 256 + lc] = acc[mf][nf][j] + bias[nf];
          }
    }
    asm volatile("s_waitcnt lgkmcnt(0)" ::: "memory");
    __builtin_amdgcn_s_barrier();
    int r = t >> 2, c0 = (t & 3) * 64;
    int slotrow = m0 + half * 128 + r;
    int tok = token_of_slot[e * CAP + slotrow];
    if (tok >= 0) {
      float f = pmax[tok];
      float* orow = out + (size_t)tok * DIM + n0 + c0;
      const float* srow = ftile + r * 256 + c0;
#pragma unroll
      for (int i = 0; i < 16; i++) {
        float4 v = *(const float4*)(srow + i * 4);
        v.x *= f; v.y *= f; v.z *= f; v.w *= f;
        *(float4*)(orow + i * 4) = v;
      }
    }
    asm volatile("s_waitcnt lgkmcnt(0)" ::: "memory");
    __builtin_amdgcn_s_barrier();
  }
}

// ---------------- dropped tokens: passthrough x ----------------
__global__ __launch_bounds__(256) void moe_fixup(const float* __restrict__ x,
                                                 const int* __restrict__ slot_of_token,
                                                 float* __restrict__ out) {
  int tok8 = blockIdx.x * 8 + (threadIdx.x >> 5);
  int lane32 = threadIdx.x & 31;
  if (slot_of_token[tok8] != NE * CAP) return;
#pragma unroll
  for (int i = 0; i < 8; i++) {
    int c = (i * 32 + lane32) * 4;
    float4 v = *(const float4*)(x + (size_t)tok8 * DIM + c);
    *(float4*)(out + (size_t)tok8 * DIM + c) = v;
  }
}

extern "C" void kernel_launch(void* const* d_in, const int* in_sizes, int n_in,
                              void* d_out, int out_size, void* d_ws, size_t ws_size,
                              hipStream_t stream) {
  (void)in_sizes; (void)n_in; (void)out_size;
  const float* x  = (const float*)d_in[0];
  const float* Wg = (const float*)d_in[1];
  const float* bg = (const float*)d_in[2];
  const float* W1 = (const float*)d_in[3];
  const float* b1 = (const float*)d_in[4];
  const float* W2 = (const float*)d_in[5];
  const float* b2 = (const float*)d_in[6];
  float* out = (float*)d_out;

  static bool attr_set = false;
  if (!attr_set) {
    hipFuncSetAttribute((const void*)moe_gemm1, hipFuncAttributeMaxDynamicSharedMemorySize, 131072);
    hipFuncSetAttribute((const void*)moe_gemm2, hipFuncAttributeMaxDynamicSharedMemorySize, 131072);
    attr_set = true;
  }

  char* p = (char*)d_ws;
  auto carve = [&](size_t bytes) -> char* {
    char* r = p;
    p += (bytes + 255) & ~(size_t)255;
    return r;
  };
  short* W1bT = (short*)carve((size_t)NE * DIM * FFD * 2);
  short* W2bT = (short*)carve((size_t)NE * DIM * FFD * 2);
  short* Xd   = (short*)carve((size_t)NE * CAP * DIM * 2);
  int* routes = (int*)carve((size_t)SEQ * 4);
  float* pmax = (float*)carve((size_t)SEQ * 4);
  int* slot_of_token = (int*)carve((size_t)SEQ * 4);
  int* token_of_slot = (int*)carve((size_t)(NE * CAP) * 4);
  int* counts = (int*)carve(256);
  size_t fixed = (size_t)(p - (char*)d_ws);

  // h rows per expert: multiple of 1024 so mch % 4 == 0 (gemm1 window decode)
  size_t avail = (ws_size > fixed + 4096) ? (ws_size - fixed - 4096) : 0;
  size_t per_row = (size_t)NE * FFD * 2;
  int rows = (int)(avail / per_row);
  rows &= ~1023;
  if (rows > CAP) rows = CAP;  // CAP = 5120 = 5*1024, mch = 20
  if (rows < 1024) rows = 1024;
  short* h = (short*)p;

  hipMemsetAsync(token_of_slot, 0xFF, (size_t)(NE * CAP) * 4, stream);
  moe_router<<<SEQ / 4, 256, 0, stream>>>(x, Wg, bg, routes, pmax);
  moe_scan<<<1, 1024, 0, stream>>>(routes, slot_of_token, token_of_slot, counts);
  moe_gather<<<NE * CAP, 256, 0, stream>>>(x, token_of_slot, Xd);
  moe_convT<<<dim3(FFD / 32, DIM / 32, NE), dim3(32, 8), 0, stream>>>(W1, W1bT, DIM, FFD);
  moe_convT<<<dim3(DIM / 32, FFD / 32, NE), dim3(32, 8), 0, stream>>>(W2, W2bT, FFD, DIM);

  for (int r0 = 0; r0 < CAP; r0 += rows) {
    int cr = (CAP - r0 < rows) ? (CAP - r0) : rows;
    int mch = cr / 256;
    moe_gemm1<<<16 * NE * mch, 512, 131072, stream>>>(Xd, W1bT, b1, h, counts, r0, rows, mch);
    moe_gemm2<<<4 * NE * mch, 512, 131072, stream>>>(h, W2bT, b2, token_of_slot, pmax, out,
                                                     counts, r0, rows, mch);
  }
  moe_fixup<<<SEQ / 8, 256, 0, stream>>>(x, slot_of_token, out);
}

// Round 10
// 1046.603 us; speedup vs baseline: 1.2065x; 1.0030x over previous
//
#include <hip/hip_runtime.h>
#include <stdint.h>

#define SEQ 32768
#define DIM 1024
#define FFD 4096
#define NE 8
#define CAP 5120

typedef __bf16 bf16x8 __attribute__((ext_vector_type(8)));
typedef float f32x4 __attribute__((ext_vector_type(4)));

__device__ __forceinline__ short f2bf(float f) {
  uint32_t u = __float_as_uint(f);
  uint32_t r = (u + 0x7fffu + ((u >> 16) & 1u)) >> 16;
  return (short)r;
}

__device__ __forceinline__ void async_copy16(const void* g, void* lds) {
  __builtin_amdgcn_global_load_lds((const __attribute__((address_space(1))) void*)g,
                                   (__attribute__((address_space(3))) void*)lds, 16, 0, 0);
}

// tanh-form gelu via __expf/__frcp_rn (verified round 7)
__device__ __forceinline__ float gelu_tanh(float v) {
  float u = v * v;
  float z = v * fmaf(0.07135371f, u, 1.5957691f);
  float E = __expf(z);
  float R = __frcp_rn(1.0f + E);
  return fmaf(-v, R, v);
}

// ---------------- router: logits in f64, argmax + p_max ----------------
__global__ __launch_bounds__(256) void moe_router(const float* __restrict__ x,
                                                  const float* __restrict__ Wg,
                                                  const float* __restrict__ bg,
                                                  int* __restrict__ routes,
                                                  float* __restrict__ pmax) {
  int token = blockIdx.x * 4 + (threadIdx.x >> 6);
  int lane = threadIdx.x & 63;
  const float* xr = x + (size_t)token * DIM;
  double acc[NE];
#pragma unroll
  for (int e = 0; e < NE; e++) acc[e] = 0.0;
#pragma unroll
  for (int i = 0; i < DIM / 64; i++) {
    int d = i * 64 + lane;
    double xv = (double)xr[d];
    const float* wr = Wg + (size_t)d * NE;
    float4 w0 = *(const float4*)(wr);
    float4 w1 = *(const float4*)(wr + 4);
    acc[0] += xv * (double)w0.x; acc[1] += xv * (double)w0.y;
    acc[2] += xv * (double)w0.z; acc[3] += xv * (double)w0.w;
    acc[4] += xv * (double)w1.x; acc[5] += xv * (double)w1.y;
    acc[6] += xv * (double)w1.z; acc[7] += xv * (double)w1.w;
  }
#pragma unroll
  for (int e = 0; e < NE; e++) {
#pragma unroll
    for (int off = 32; off >= 1; off >>= 1) acc[e] += __shfl_xor(acc[e], off);
  }
  if (lane == 0) {
    double l[NE];
#pragma unroll
    for (int e = 0; e < NE; e++) l[e] = acc[e] + (double)bg[e];
    int am = 0;
#pragma unroll
    for (int e = 1; e < NE; e++) if (l[e] > l[am]) am = e;
    double s = 0.0;
#pragma unroll
    for (int e = 0; e < NE; e++) s += exp(l[e] - l[am]);
    routes[token] = am;
    pmax[token] = (float)(1.0 / s);
  }
}

// ---------------- scan: per-expert FCFS positions ----------------
__global__ __launch_bounds__(1024) void moe_scan(const int* __restrict__ routes,
                                                 int* __restrict__ slot_of_token,
                                                 int* __restrict__ token_of_slot,
                                                 int* __restrict__ counts) {
  __shared__ int wtot[16][NE];
  __shared__ int woff[16][NE];
  int t = threadIdx.x, lane = t & 63, w = t >> 6;
  int cnt[NE];
#pragma unroll
  for (int e = 0; e < NE; e++) cnt[e] = 0;
  int base = t * 32;
  for (int i = 0; i < 32; i++) {
    int r = routes[base + i];
#pragma unroll
    for (int e = 0; e < NE; e++) cnt[e] += (r == e) ? 1 : 0;
  }
  int incl[NE];
#pragma unroll
  for (int e = 0; e < NE; e++) {
    int v = cnt[e];
#pragma unroll
    for (int off = 1; off < 64; off <<= 1) {
      int o = __shfl_up(v, off);
      if (lane >= off) v += o;
    }
    incl[e] = v;
    if (lane == 63) wtot[w][e] = v;
  }
  __syncthreads();
  if (t < NE) {
    int run = 0;
    for (int ww = 0; ww < 16; ww++) {
      int tmp = wtot[ww][t];
      woff[ww][t] = run;
      run += tmp;
    }
    counts[t] = run;
  }
  __syncthreads();
  int pos[NE];
#pragma unroll
  for (int e = 0; e < NE; e++) pos[e] = woff[w][e] + incl[e] - cnt[e];
  for (int i = 0; i < 32; i++) {
    int tok = base + i;
    int r = routes[tok];
    int p = 0;
#pragma unroll
    for (int e = 0; e < NE; e++)
      if (r == e) { p = pos[e]; pos[e] = p + 1; }
    bool kept = p < CAP;
    int slot = kept ? r * CAP + p : NE * CAP;
    slot_of_token[tok] = slot;
    if (kept) token_of_slot[slot] = tok;
  }
}

// ---------------- gather dispatch buffer (bf16), zeros for empty slots ----------------
__global__ __launch_bounds__(256) void moe_gather(const float* __restrict__ x,
                                                  const int* __restrict__ token_of_slot,
                                                  short* __restrict__ Xd) {
  int slot = blockIdx.x;
  int tok = token_of_slot[slot];
  int t = threadIdx.x;
  short* dst = Xd + (size_t)slot * DIM + t * 4;
  short4 v;
  if (tok < 0) {
    v.x = 0; v.y = 0; v.z = 0; v.w = 0;
  } else {
    float4 f = *(const float4*)(x + (size_t)tok * DIM + t * 4);
    v.x = f2bf(f.x); v.y = f2bf(f.y); v.z = f2bf(f.z); v.w = f2bf(f.w);
  }
  *(short4*)dst = v;
}

// ---------------- convert f32 [E][K][N] -> bf16 [E][N][K] ----------------
__global__ __launch_bounds__(256) void moe_convT(const float* __restrict__ W,
                                                 short* __restrict__ WT, int K, int N) {
  __shared__ float tile[32][33];
  int e = blockIdx.z;
  const float* We = W + (size_t)e * K * N;
  short* WTe = WT + (size_t)e * K * N;
  int n0 = blockIdx.x * 32, k0 = blockIdx.y * 32;
  int tx = threadIdx.x, ty = threadIdx.y;
#pragma unroll
  for (int i = 0; i < 4; i++)
    tile[ty + i * 8][tx] = We[(size_t)(k0 + ty + i * 8) * N + n0 + tx];
  __syncthreads();
#pragma unroll
  for (int i = 0; i < 4; i++)
    WTe[(size_t)(n0 + ty + i * 8) * K + k0 + tx] = f2bf(tile[tx][ty + i * 8]);
}

// ================= 256x256 8-phase GEMM mainloop (A+B LDS, verified r4-r9) =============
// LDS bytes: A buf0 [0,32768) A buf1 [32768,65536) B buf0 [65536,98304) B buf1 [98304,131072)
// Swizzle: kbyte ^= (lrow&7)<<4 on global SOURCE (pre-swizzle) and on ds_read;
// gload_lds dest stays linear (rule #21).
__device__ __forceinline__ void mainloop256(const short* __restrict__ Ag, int lda,
                                            const short* __restrict__ Bg, int ldb,
                                            int NT, short* smem, f32x4 acc[8][4],
                                            int wr, int wc, int l, int t) {
  const int cb = ((t & 7) << 4) ^ (((t >> 3) & 7) << 4);
  const int rs = t >> 3;
  const int rb = ((rs >> 5) << 6) + (rs & 31);
  const size_t la2 = (size_t)lda * 2, lb2 = (size_t)ldb * 2;
  const char* pa0q0 = (const char*)Ag + (size_t)(rs)       * la2 + cb;
  const char* pa0q1 = (const char*)Ag + (size_t)(128 + rs) * la2 + cb;
  const char* pa1q0 = (const char*)Ag + (size_t)(64 + rs)  * la2 + cb;
  const char* pa1q1 = (const char*)Ag + (size_t)(192 + rs) * la2 + cb;
  const char* pb0q0 = (const char*)Bg + (size_t)(rb)       * lb2 + cb;
  const char* pb0q1 = (const char*)Bg + (size_t)(128 + rb) * lb2 + cb;
  const char* pb1q0 = (const char*)Bg + (size_t)(32 + rb)  * lb2 + cb;
  const char* pb1q1 = (const char*)Bg + (size_t)(160 + rb) * lb2 + cb;
  short* dA = smem + t * 8;
  short* dB = smem + 32768 + t * 8;

  auto STG = [&](const char*& p0, const char*& p1, short* d) {
    async_copy16(p0, d);
    async_copy16(p1, d + 4096);
    p0 += 128; p1 += 128;
  };

  STG(pa0q0, pa0q1, dA);
  STG(pb0q0, pb0q1, dB);
  STG(pa1q0, pa1q1, dA + 8192);
  STG(pb1q0, pb1q1, dB + 8192);
  STG(pa0q0, pa0q1, dA + 16384);
  STG(pb0q0, pb0q1, dB + 16384);
  STG(pa1q0, pa1q1, dA + 16384 + 8192);
  asm volatile("s_waitcnt vmcnt(6)" ::: "memory");
  __builtin_amdgcn_s_barrier();

  const int l15 = l & 15;
  const int kh16 = (l >> 4) << 4;
  const int swz = (l15 & 7) << 4;
  const char* paK0 = (const char*)smem + (wr * 64 + l15) * 128 + (kh16 ^ swz);
  const char* paK1 = (const char*)smem + (wr * 64 + l15) * 128 + ((64 + kh16) ^ swz);
  const char* pbK0 = (const char*)smem + 65536 + (wc * 32 + l15) * 128 + (kh16 ^ swz);
  const char* pbK1 = (const char*)smem + 65536 + (wc * 32 + l15) * 128 + ((64 + kh16) ^ swz);

  for (int T = 0; T < NT; T++) {
    const int selByte = (T & 1) << 15;
    const int selSh = (T & 1) << 14;
    const int selShN = ((T + 1) & 1) << 14;
    const char* pa0 = paK0 + selByte;
    const char* pa1 = paK1 + selByte;
    const char* pb0 = pbK0 + selByte;
    const char* pb1 = pbK1 + selByte;
    bf16x8 a[4][2], b0[2][2], b1[2][2];
#pragma unroll
    for (int mf = 0; mf < 4; mf++) {
      a[mf][0] = *(const bf16x8*)(pa0 + mf * 2048);
      a[mf][1] = *(const bf16x8*)(pa1 + mf * 2048);
    }
#pragma unroll
    for (int nf = 0; nf < 2; nf++) {
      b0[nf][0] = *(const bf16x8*)(pb0 + nf * 2048);
      b0[nf][1] = *(const bf16x8*)(pb1 + nf * 2048);
    }
    if (T + 1 < NT) STG(pb1q0, pb1q1, dB + 8192 + selShN);
    __builtin_amdgcn_s_barrier();
    __builtin_amdgcn_s_setprio(1);
#pragma unroll
    for (int mf = 0; mf < 4; mf++)
#pragma unroll
      for (int nf = 0; nf < 2; nf++)
#pragma unroll
        for (int kk = 0; kk < 2; kk++)
          acc[mf][nf] = __builtin_amdgcn_mfma_f32_16x16x32_bf16(a[mf][kk], b0[nf][kk], acc[mf][nf], 0, 0, 0);
    __builtin_amdgcn_s_setprio(0);
    __builtin_amdgcn_s_barrier();
#pragma unroll
    for (int nf = 0; nf < 2; nf++) {
      b1[nf][0] = *(const bf16x8*)(pb0 + 16384 + nf * 2048);
      b1[nf][1] = *(const bf16x8*)(pb1 + 16384 + nf * 2048);
    }
    if (T + 2 < NT) STG(pa0q0, pa0q1, dA + selSh);
    __builtin_amdgcn_s_barrier();
    __builtin_amdgcn_s_setprio(1);
#pragma unroll
    for (int mf = 0; mf < 4; mf++)
#pragma unroll
      for (int nf = 0; nf < 2; nf++)
#pragma unroll
        for (int kk = 0; kk < 2; kk++)
          acc[mf][nf + 2] = __builtin_amdgcn_mfma_f32_16x16x32_bf16(a[mf][kk], b1[nf][kk], acc[mf][nf + 2], 0, 0, 0);
    __builtin_amdgcn_s_setprio(0);
    __builtin_amdgcn_s_barrier();
#pragma unroll
    for (int mf = 0; mf < 4; mf++) {
      a[mf][0] = *(const bf16x8*)(pa0 + 16384 + mf * 2048);
      a[mf][1] = *(const bf16x8*)(pa1 + 16384 + mf * 2048);
    }
    if (T + 2 < NT) STG(pb0q0, pb0q1, dB + selSh);
    __builtin_amdgcn_s_barrier();
    __builtin_amdgcn_s_setprio(1);
#pragma unroll
    for (int mf = 0; mf < 4; mf++)
#pragma unroll
      for (int nf = 0; nf < 2; nf++)
#pragma unroll
        for (int kk = 0; kk < 2; kk++)
          acc[mf + 4][nf + 2] = __builtin_amdgcn_mfma_f32_16x16x32_bf16(a[mf][kk], b1[nf][kk], acc[mf + 4][nf + 2], 0, 0, 0);
    __builtin_amdgcn_s_setprio(0);
    __builtin_amdgcn_s_barrier();
    if (T + 2 < NT) STG(pa1q0, pa1q1, dA + 8192 + selSh);
    __builtin_amdgcn_s_barrier();
    __builtin_amdgcn_s_setprio(1);
#pragma unroll
    for (int mf = 0; mf < 4; mf++)
#pragma unroll
      for (int nf = 0; nf < 2; nf++)
#pragma unroll
        for (int kk = 0; kk < 2; kk++)
          acc[mf + 4][nf] = __builtin_amdgcn_mfma_f32_16x16x32_bf16(a[mf][kk], b0[nf][kk], acc[mf + 4][nf], 0, 0, 0);
    __builtin_amdgcn_s_setprio(0);
    if (T + 2 < NT) asm volatile("s_waitcnt vmcnt(6)" ::: "memory");
    else            asm volatile("s_waitcnt vmcnt(0)" ::: "memory");
    __builtin_amdgcn_s_barrier();
  }
  asm volatile("s_waitcnt vmcnt(0) lgkmcnt(0)" ::: "memory");
  __builtin_amdgcn_s_barrier();
}

// ---------------- GEMM1: h = gelu(Xd @ W1 + b1), bf16 out ----------------
// L2-window grid decode (verified round 9): 4Mx8N windows, col-major per XCD.
#define PITCH1 272  // shorts; 128 x 272 x 2B = 69,632 B (fits 128 KB)
__global__ __launch_bounds__(512, 2) void moe_gemm1(const short* __restrict__ Xd,
                                                    const short* __restrict__ W1bT,
                                                    const float* __restrict__ b1,
                                                    short* __restrict__ h,
                                                    const int* __restrict__ counts,
                                                    int m_base, int rows, int mch) {
  extern __shared__ short smem[];
  int bid = blockIdx.x;
  int xcd = bid & 7;
  int k = bid >> 3;           // 0 .. 2*NE*mch-1 (per-XCD sequence)
  int sub = k & 31;           // position in 4Mx8N window
  int win = k >> 5;           // per-XCD window index
  int Wm = NE * mch / 4;      // M-windows
  int g = win * 8 + xcd;      // global window id, col-major (wm fast, wn slow)
  int wm = g % Wm;
  int wn = g / Wm;            // 0 or 1
  int mlin = wm * 4 + (sub >> 3);
  int nn = wn * 8 + (sub & 7);
  int e = mlin / mch;
  int mm = mlin - e * mch;
  int cnt = counts[e]; if (cnt > CAP) cnt = CAP;
  int m0 = m_base + mm * 256;
  if (m0 >= cnt) return;
  int n0 = nn * 256;
  int t = threadIdx.x, l = t & 63, wid = t >> 6;
  int wr = wid >> 2, wc = wid & 3;
  const short* Ag = Xd + ((size_t)e * CAP + m0) * DIM;
  const short* Bg = W1bT + ((size_t)e * FFD + n0) * DIM;
  f32x4 acc[8][4];
#pragma unroll
  for (int mf = 0; mf < 8; mf++)
#pragma unroll
    for (int nf = 0; nf < 4; nf++) acc[mf][nf] = (f32x4){0.f, 0.f, 0.f, 0.f};
  mainloop256(Ag, DIM, Bg, DIM, DIM / 64, smem, acc, wr, wc, l, t);

  int l15 = l & 15, q4 = (l >> 4) * 4;
  float bias[4];
#pragma unroll
  for (int nf = 0; nf < 4; nf++)
    bias[nf] = b1[(size_t)e * FFD + n0 + wc * 64 + nf * 16 + l15];
#pragma unroll
  for (int half = 0; half < 2; half++) {
    if (wr == half) {
#pragma unroll
      for (int mf = 0; mf < 8; mf++)
#pragma unroll
        for (int nf = 0; nf < 4; nf++)
#pragma unroll
          for (int j = 0; j < 4; j++) {
            int lr = mf * 16 + q4 + j;
            int lc = wc * 64 + nf * 16 + l15;
            float v = acc[mf][nf][j] + bias[nf];
            smem[lr * PITCH1 + lc] = f2bf(gelu_tanh(v));
          }
    }
    asm volatile("s_waitcnt lgkmcnt(0)" ::: "memory");
    __builtin_amdgcn_s_barrier();
    int r = t >> 2, c0 = (t & 3) * 64;
    short* hrow = h + ((size_t)e * rows + (m0 - m_base) + half * 128 + r) * FFD + n0 + c0;
    const short* srow = smem + r * PITCH1 + c0;
#pragma unroll
    for (int i = 0; i < 8; i++)
      *(int4*)(hrow + i * 8) = *(const int4*)(srow + i * 8);
    asm volatile("s_waitcnt lgkmcnt(0)" ::: "memory");
    __builtin_amdgcn_s_barrier();
  }
}

// ---------------- GEMM2: out[token] = (h @ W2 + b2) * p_max, scatter ----------------
// Expert-pinned decode: XCD e owns expert e (8 experts <-> 8 XCDs). Per-XCD sweep:
// 4Mx4N windows, M-major. B-set (W2 of e, 8MB) stays L2/L3-hot for the whole sweep;
// the 4 N-sharers of each 2MB h A-panel are adjacent slots -> co-dispatched -> L2 hit.
// Requires mch % 4 == 0 (launcher clamps rows to multiples of 1024).
__global__ __launch_bounds__(512, 2) void moe_gemm2(const short* __restrict__ h,
                                                    const short* __restrict__ W2bT,
                                                    const float* __restrict__ b2,
                                                    const int* __restrict__ token_of_slot,
                                                    const float* __restrict__ pmax,
                                                    float* __restrict__ out,
                                                    const int* __restrict__ counts,
                                                    int m_base, int rows, int mch) {
  extern __shared__ short smem[];
  int bid = blockIdx.x;
  int e = bid & 7;            // expert == XCD
  int k = bid >> 3;           // 0 .. 4*mch-1 per XCD
  int sub = k & 15;           // 4M x 4N window
  int wm = k >> 4;            // 0 .. mch/4-1
  int nn = sub & 3;
  int mm = wm * 4 + (sub >> 2);
  int cnt = counts[e]; if (cnt > CAP) cnt = CAP;
  int m0 = m_base + mm * 256;
  if (m0 >= cnt) return;
  int n0 = nn * 256;
  int t = threadIdx.x, l = t & 63, wid = t >> 6;
  int wr = wid >> 2, wc = wid & 3;
  const short* Ag = h + ((size_t)e * rows + (m0 - m_base)) * FFD;
  const short* Bg = W2bT + ((size_t)e * DIM + n0) * FFD;
  f32x4 acc[8][4];
#pragma unroll
  for (int mf = 0; mf < 8; mf++)
#pragma unroll
    for (int nf = 0; nf < 4; nf++) acc[mf][nf] = (f32x4){0.f, 0.f, 0.f, 0.f};
  mainloop256(Ag, FFD, Bg, FFD, FFD / 64, smem, acc, wr, wc, l, t);

  float* ftile = (float*)smem;  // 128 x 256 f32 = 128 KB (exact fit)
  int l15 = l & 15, q4 = (l >> 4) * 4;
  float bias[4];
#pragma unroll
  for (int nf = 0; nf < 4; nf++)
    bias[nf] = b2[(size_t)e * DIM + n0 + wc * 64 + nf * 16 + l15];
#pragma unroll
  for (int half = 0; half < 2; half++) {
    if (wr == half) {
#pragma unroll
      for (int mf = 0; mf < 8; mf++)
#pragma unroll
        for (int nf = 0; nf < 4; nf++)
#pragma unroll
          for (int j = 0; j < 4; j++) {
            int lr = mf * 16 + q4 + j;
            int lc = wc * 64 + nf * 16 + l15;
            ftile[lr * 256 + lc] = acc[mf][nf][j] + bias[nf];
          }
    }
    asm volatile("s_waitcnt lgkmcnt(0)" ::: "memory");
    __builtin_amdgcn_s_barrier();
    int r = t >> 2, c0 = (t & 3) * 64;
    int slotrow = m0 + half * 128 + r;
    int tok = token_of_slot[e * CAP + slotrow];
    if (tok >= 0) {
      float f = pmax[tok];
      float* orow = out + (size_t)tok * DIM + n0 + c0;
      const float* srow = ftile + r * 256 + c0;
#pragma unroll
      for (int i = 0; i < 16; i++) {
        float4 v = *(const float4*)(srow + i * 4);
        v.x *= f; v.y *= f; v.z *= f; v.w *= f;
        *(float4*)(orow + i * 4) = v;
      }
    }
    asm volatile("s_waitcnt lgkmcnt(0)" ::: "memory");
    __builtin_amdgcn_s_barrier();
  }
}

// ---------------- dropped tokens: passthrough x ----------------
__global__ __launch_bounds__(256) void moe_fixup(const float* __restrict__ x,
                                                 const int* __restrict__ slot_of_token,
                                                 float* __restrict__ out) {
  int tok8 = blockIdx.x * 8 + (threadIdx.x >> 5);
  int lane32 = threadIdx.x & 31;
  if (slot_of_token[tok8] != NE * CAP) return;
#pragma unroll
  for (int i = 0; i < 8; i++) {
    int c = (i * 32 + lane32) * 4;
    float4 v = *(const float4*)(x + (size_t)tok8 * DIM + c);
    *(float4*)(out + (size_t)tok8 * DIM + c) = v;
  }
}

extern "C" void kernel_launch(void* const* d_in, const int* in_sizes, int n_in,
                              void* d_out, int out_size, void* d_ws, size_t ws_size,
                              hipStream_t stream) {
  (void)in_sizes; (void)n_in; (void)out_size;
  const float* x  = (const float*)d_in[0];
  const float* Wg = (const float*)d_in[1];
  const float* bg = (const float*)d_in[2];
  const float* W1 = (const float*)d_in[3];
  const float* b1 = (const float*)d_in[4];
  const float* W2 = (const float*)d_in[5];
  const float* b2 = (const float*)d_in[6];
  float* out = (float*)d_out;

  static bool attr_set = false;
  if (!attr_set) {
    hipFuncSetAttribute((const void*)moe_gemm1, hipFuncAttributeMaxDynamicSharedMemorySize, 131072);
    hipFuncSetAttribute((const void*)moe_gemm2, hipFuncAttributeMaxDynamicSharedMemorySize, 131072);
    attr_set = true;
  }

  char* p = (char*)d_ws;
  auto carve = [&](size_t bytes) -> char* {
    char* r = p;
    p += (bytes + 255) & ~(size_t)255;
    return r;
  };
  short* W1bT = (short*)carve((size_t)NE * DIM * FFD * 2);
  short* W2bT = (short*)carve((size_t)NE * DIM * FFD * 2);
  short* Xd   = (short*)carve((size_t)NE * CAP * DIM * 2);
  int* routes = (int*)carve((size_t)SEQ * 4);
  float* pmax = (float*)carve((size_t)SEQ * 4);
  int* slot_of_token = (int*)carve((size_t)SEQ * 4);
  int* token_of_slot = (int*)carve((size_t)(NE * CAP) * 4);
  int* counts = (int*)carve(256);
  size_t fixed = (size_t)(p - (char*)d_ws);

  // h rows per expert: multiple of 1024 so mch % 4 == 0 (window decodes)
  size_t avail = (ws_size > fixed + 4096) ? (ws_size - fixed - 4096) : 0;
  size_t per_row = (size_t)NE * FFD * 2;
  int rows = (int)(avail / per_row);
  rows &= ~1023;
  if (rows > CAP) rows = CAP;  // CAP = 5120 = 5*1024, mch = 20
  if (rows < 1024) rows = 1024;
  short* h = (short*)p;

  hipMemsetAsync(token_of_slot, 0xFF, (size_t)(NE * CAP) * 4, stream);
  moe_router<<<SEQ / 4, 256, 0, stream>>>(x, Wg, bg, routes, pmax);
  moe_scan<<<1, 1024, 0, stream>>>(routes, slot_of_token, token_of_slot, counts);
  moe_gather<<<NE * CAP, 256, 0, stream>>>(x, token_of_slot, Xd);
  moe_convT<<<dim3(FFD / 32, DIM / 32, NE), dim3(32, 8), 0, stream>>>(W1, W1bT, DIM, FFD);
  moe_convT<<<dim3(DIM / 32, FFD / 32, NE), dim3(32, 8), 0, stream>>>(W2, W2bT, FFD, DIM);

  for (int r0 = 0; r0 < CAP; r0 += rows) {
    int cr = (CAP - r0 < rows) ? (CAP - r0) : rows;
    int mch = cr / 256;
    moe_gemm1<<<16 * NE * mch, 512, 131072, stream>>>(Xd, W1bT, b1, h, counts, r0, rows, mch);
    moe_gemm2<<<4 * NE * mch, 512, 131072, stream>>>(h, W2bT, b2, token_of_slot, pmax, out,
                                                     counts, r0, rows, mch);
  }
  moe_fixup<<<SEQ / 8, 256, 0, stream>>>(x, slot_of_token, out);
}

// Round 11
// 986.545 us; speedup vs baseline: 1.2800x; 1.0609x over previous
//
#include <hip/hip_runtime.h>
#include <stdint.h>

#define SEQ 32768
#define DIM 1024
#define FFD 4096
#define NE 8
#define CAP 5120

typedef __bf16 bf16x8 __attribute__((ext_vector_type(8)));
typedef float f32x4 __attribute__((ext_vector_type(4)));

__device__ __forceinline__ short f2bf(float f) {
  uint32_t u = __float_as_uint(f);
  uint32_t r = (u + 0x7fffu + ((u >> 16) & 1u)) >> 16;
  return (short)r;
}

__device__ __forceinline__ void async_copy16(const void* g, void* lds) {
  __builtin_amdgcn_global_load_lds((const __attribute__((address_space(1))) void*)g,
                                   (__attribute__((address_space(3))) void*)lds, 16, 0, 0);
}

// tanh-form gelu via __expf/__frcp_rn (verified round 7)
__device__ __forceinline__ float gelu_tanh(float v) {
  float u = v * v;
  float z = v * fmaf(0.07135371f, u, 1.5957691f);
  float E = __expf(z);
  float R = __frcp_rn(1.0f + E);
  return fmaf(-v, R, v);
}

// ---------------- router: logits in f64, argmax + p_max ----------------
__global__ __launch_bounds__(256) void moe_router(const float* __restrict__ x,
                                                  const float* __restrict__ Wg,
                                                  const float* __restrict__ bg,
                                                  int* __restrict__ routes,
                                                  float* __restrict__ pmax) {
  int token = blockIdx.x * 4 + (threadIdx.x >> 6);
  int lane = threadIdx.x & 63;
  const float* xr = x + (size_t)token * DIM;
  double acc[NE];
#pragma unroll
  for (int e = 0; e < NE; e++) acc[e] = 0.0;
#pragma unroll
  for (int i = 0; i < DIM / 64; i++) {
    int d = i * 64 + lane;
    double xv = (double)xr[d];
    const float* wr = Wg + (size_t)d * NE;
    float4 w0 = *(const float4*)(wr);
    float4 w1 = *(const float4*)(wr + 4);
    acc[0] += xv * (double)w0.x; acc[1] += xv * (double)w0.y;
    acc[2] += xv * (double)w0.z; acc[3] += xv * (double)w0.w;
    acc[4] += xv * (double)w1.x; acc[5] += xv * (double)w1.y;
    acc[6] += xv * (double)w1.z; acc[7] += xv * (double)w1.w;
  }
#pragma unroll
  for (int e = 0; e < NE; e++) {
#pragma unroll
    for (int off = 32; off >= 1; off >>= 1) acc[e] += __shfl_xor(acc[e], off);
  }
  if (lane == 0) {
    double l[NE];
#pragma unroll
    for (int e = 0; e < NE; e++) l[e] = acc[e] + (double)bg[e];
    int am = 0;
#pragma unroll
    for (int e = 1; e < NE; e++) if (l[e] > l[am]) am = e;
    double s = 0.0;
#pragma unroll
    for (int e = 0; e < NE; e++) s += exp(l[e] - l[am]);
    routes[token] = am;
    pmax[token] = (float)(1.0 / s);
  }
}

// ---------------- scan: per-expert FCFS positions, one block per expert --------------
// Block E handles expert E only: inits its token_of_slot range, counts/scans matches
// in token order (FCFS), writes slot_of_token for its tokens (each token has exactly
// one expert -> full coverage), token_of_slot for kept slots, counts[E].
__global__ __launch_bounds__(1024) void moe_scan8(const int* __restrict__ routes,
                                                  int* __restrict__ slot_of_token,
                                                  int* __restrict__ token_of_slot,
                                                  int* __restrict__ counts) {
  int E = blockIdx.x;
  __shared__ int wtot[16];
  __shared__ int woff[16];
  int t = threadIdx.x, lane = t & 63, w = t >> 6;
  for (int i = t; i < CAP; i += 1024) token_of_slot[E * CAP + i] = -1;
  int base = t * 32;
  int rloc[32];
  int cnt = 0;
#pragma unroll
  for (int i = 0; i < 32; i++) {
    int r = routes[base + i];
    rloc[i] = r;
    cnt += (r == E) ? 1 : 0;
  }
  int v = cnt;
#pragma unroll
  for (int off = 1; off < 64; off <<= 1) {
    int o = __shfl_up(v, off);
    if (lane >= off) v += o;
  }
  if (lane == 63) wtot[w] = v;
  __syncthreads();
  if (t == 0) {
    int run = 0;
    for (int ww = 0; ww < 16; ww++) { woff[ww] = run; run += wtot[ww]; }
    counts[E] = run;
  }
  __syncthreads();
  int pos = woff[w] + v - cnt;  // exclusive prefix for this thread
#pragma unroll
  for (int i = 0; i < 32; i++) {
    int tok = base + i;
    if (rloc[i] == E) {
      bool kept = pos < CAP;
      slot_of_token[tok] = kept ? E * CAP + pos : NE * CAP;
      if (kept) token_of_slot[E * CAP + pos] = tok;
      pos++;
    }
  }
}

// ---------------- gather dispatch buffer (bf16), zeros for empty slots ----------------
__global__ __launch_bounds__(256) void moe_gather(const float* __restrict__ x,
                                                  const int* __restrict__ token_of_slot,
                                                  short* __restrict__ Xd) {
  int slot = blockIdx.x;
  int tok = token_of_slot[slot];
  int t = threadIdx.x;
  short* dst = Xd + (size_t)slot * DIM + t * 4;
  short4 v;
  if (tok < 0) {
    v.x = 0; v.y = 0; v.z = 0; v.w = 0;
  } else {
    float4 f = *(const float4*)(x + (size_t)tok * DIM + t * 4);
    v.x = f2bf(f.x); v.y = f2bf(f.y); v.z = f2bf(f.z); v.w = f2bf(f.w);
  }
  *(short4*)dst = v;
}

// ------- fused convert f32 [E][K][N] -> bf16 [E][N][K], both W1 (z<8) and W2 (z>=8) ---
// float4 loads (16B/lane), short4 stores (8B/lane); 32x32 LDS transpose tile, pad 33.
__global__ __launch_bounds__(256) void moe_convT2(const float* __restrict__ W1,
                                                  const float* __restrict__ W2,
                                                  short* __restrict__ WT1,
                                                  short* __restrict__ WT2) {
  __shared__ float tile[32][33];
  int z = blockIdx.z;
  const float* W;
  short* WT;
  int K, N;
  if (z < NE) { W = W1 + (size_t)z * DIM * FFD; WT = WT1 + (size_t)z * DIM * FFD; K = DIM; N = FFD; }
  else        { W = W2 + (size_t)(z - NE) * DIM * FFD; WT = WT2 + (size_t)(z - NE) * DIM * FFD; K = FFD; N = DIM; }
  int nb = N >> 5;
  int idx = blockIdx.x;
  int n0 = (idx % nb) * 32, k0 = (idx / nb) * 32;
  int t = threadIdx.x;
  int r = t >> 3, c4 = (t & 7) * 4;
  float4 v = *(const float4*)(W + (size_t)(k0 + r) * N + n0 + c4);
  tile[r][c4] = v.x; tile[r][c4 + 1] = v.y; tile[r][c4 + 2] = v.z; tile[r][c4 + 3] = v.w;
  __syncthreads();
  int rn = t >> 3, k4 = (t & 7) * 4;
  short4 o;
  o.x = f2bf(tile[k4][rn]);
  o.y = f2bf(tile[k4 + 1][rn]);
  o.z = f2bf(tile[k4 + 2][rn]);
  o.w = f2bf(tile[k4 + 3][rn]);
  *(short4*)(WT + (size_t)(n0 + rn) * K + k0 + k4) = o;
}

// ================= 256x256 8-phase GEMM mainloop (A+B LDS, verified r4-r10) ============
// LDS bytes: A buf0 [0,32768) A buf1 [32768,65536) B buf0 [65536,98304) B buf1 [98304,131072)
// Swizzle: kbyte ^= (lrow&7)<<4 on global SOURCE (pre-swizzle) and on ds_read;
// gload_lds dest stays linear (rule #21).
__device__ __forceinline__ void mainloop256(const short* __restrict__ Ag, int lda,
                                            const short* __restrict__ Bg, int ldb,
                                            int NT, short* smem, f32x4 acc[8][4],
                                            int wr, int wc, int l, int t) {
  const int cb = ((t & 7) << 4) ^ (((t >> 3) & 7) << 4);
  const int rs = t >> 3;
  const int rb = ((rs >> 5) << 6) + (rs & 31);
  const size_t la2 = (size_t)lda * 2, lb2 = (size_t)ldb * 2;
  const char* pa0q0 = (const char*)Ag + (size_t)(rs)       * la2 + cb;
  const char* pa0q1 = (const char*)Ag + (size_t)(128 + rs) * la2 + cb;
  const char* pa1q0 = (const char*)Ag + (size_t)(64 + rs)  * la2 + cb;
  const char* pa1q1 = (const char*)Ag + (size_t)(192 + rs) * la2 + cb;
  const char* pb0q0 = (const char*)Bg + (size_t)(rb)       * lb2 + cb;
  const char* pb0q1 = (const char*)Bg + (size_t)(128 + rb) * lb2 + cb;
  const char* pb1q0 = (const char*)Bg + (size_t)(32 + rb)  * lb2 + cb;
  const char* pb1q1 = (const char*)Bg + (size_t)(160 + rb) * lb2 + cb;
  short* dA = smem + t * 8;
  short* dB = smem + 32768 + t * 8;

  auto STG = [&](const char*& p0, const char*& p1, short* d) {
    async_copy16(p0, d);
    async_copy16(p1, d + 4096);
    p0 += 128; p1 += 128;
  };

  STG(pa0q0, pa0q1, dA);
  STG(pb0q0, pb0q1, dB);
  STG(pa1q0, pa1q1, dA + 8192);
  STG(pb1q0, pb1q1, dB + 8192);
  STG(pa0q0, pa0q1, dA + 16384);
  STG(pb0q0, pb0q1, dB + 16384);
  STG(pa1q0, pa1q1, dA + 16384 + 8192);
  asm volatile("s_waitcnt vmcnt(6)" ::: "memory");
  __builtin_amdgcn_s_barrier();

  const int l15 = l & 15;
  const int kh16 = (l >> 4) << 4;
  const int swz = (l15 & 7) << 4;
  const char* paK0 = (const char*)smem + (wr * 64 + l15) * 128 + (kh16 ^ swz);
  const char* paK1 = (const char*)smem + (wr * 64 + l15) * 128 + ((64 + kh16) ^ swz);
  const char* pbK0 = (const char*)smem + 65536 + (wc * 32 + l15) * 128 + (kh16 ^ swz);
  const char* pbK1 = (const char*)smem + 65536 + (wc * 32 + l15) * 128 + ((64 + kh16) ^ swz);

  for (int T = 0; T < NT; T++) {
    const int selByte = (T & 1) << 15;
    const int selSh = (T & 1) << 14;
    const int selShN = ((T + 1) & 1) << 14;
    const char* pa0 = paK0 + selByte;
    const char* pa1 = paK1 + selByte;
    const char* pb0 = pbK0 + selByte;
    const char* pb1 = pbK1 + selByte;
    bf16x8 a[4][2], b0[2][2], b1[2][2];
#pragma unroll
    for (int mf = 0; mf < 4; mf++) {
      a[mf][0] = *(const bf16x8*)(pa0 + mf * 2048);
      a[mf][1] = *(const bf16x8*)(pa1 + mf * 2048);
    }
#pragma unroll
    for (int nf = 0; nf < 2; nf++) {
      b0[nf][0] = *(const bf16x8*)(pb0 + nf * 2048);
      b0[nf][1] = *(const bf16x8*)(pb1 + nf * 2048);
    }
    if (T + 1 < NT) STG(pb1q0, pb1q1, dB + 8192 + selShN);
    __builtin_amdgcn_s_barrier();
    __builtin_amdgcn_s_setprio(1);
#pragma unroll
    for (int mf = 0; mf < 4; mf++)
#pragma unroll
      for (int nf = 0; nf < 2; nf++)
#pragma unroll
        for (int kk = 0; kk < 2; kk++)
          acc[mf][nf] = __builtin_amdgcn_mfma_f32_16x16x32_bf16(a[mf][kk], b0[nf][kk], acc[mf][nf], 0, 0, 0);
    __builtin_amdgcn_s_setprio(0);
    __builtin_amdgcn_s_barrier();
#pragma unroll
    for (int nf = 0; nf < 2; nf++) {
      b1[nf][0] = *(const bf16x8*)(pb0 + 16384 + nf * 2048);
      b1[nf][1] = *(const bf16x8*)(pb1 + 16384 + nf * 2048);
    }
    if (T + 2 < NT) STG(pa0q0, pa0q1, dA + selSh);
    __builtin_amdgcn_s_barrier();
    __builtin_amdgcn_s_setprio(1);
#pragma unroll
    for (int mf = 0; mf < 4; mf++)
#pragma unroll
      for (int nf = 0; nf < 2; nf++)
#pragma unroll
        for (int kk = 0; kk < 2; kk++)
          acc[mf][nf + 2] = __builtin_amdgcn_mfma_f32_16x16x32_bf16(a[mf][kk], b1[nf][kk], acc[mf][nf + 2], 0, 0, 0);
    __builtin_amdgcn_s_setprio(0);
    __builtin_amdgcn_s_barrier();
#pragma unroll
    for (int mf = 0; mf < 4; mf++) {
      a[mf][0] = *(const bf16x8*)(pa0 + 16384 + mf * 2048);
      a[mf][1] = *(const bf16x8*)(pa1 + 16384 + mf * 2048);
    }
    if (T + 2 < NT) STG(pb0q0, pb0q1, dB + selSh);
    __builtin_amdgcn_s_barrier();
    __builtin_amdgcn_s_setprio(1);
#pragma unroll
    for (int mf = 0; mf < 4; mf++)
#pragma unroll
      for (int nf = 0; nf < 2; nf++)
#pragma unroll
        for (int kk = 0; kk < 2; kk++)
          acc[mf + 4][nf + 2] = __builtin_amdgcn_mfma_f32_16x16x32_bf16(a[mf][kk], b1[nf][kk], acc[mf + 4][nf + 2], 0, 0, 0);
    __builtin_amdgcn_s_setprio(0);
    __builtin_amdgcn_s_barrier();
    if (T + 2 < NT) STG(pa1q0, pa1q1, dA + 8192 + selSh);
    __builtin_amdgcn_s_barrier();
    __builtin_amdgcn_s_setprio(1);
#pragma unroll
    for (int mf = 0; mf < 4; mf++)
#pragma unroll
      for (int nf = 0; nf < 2; nf++)
#pragma unroll
        for (int kk = 0; kk < 2; kk++)
          acc[mf + 4][nf] = __builtin_amdgcn_mfma_f32_16x16x32_bf16(a[mf][kk], b0[nf][kk], acc[mf + 4][nf], 0, 0, 0);
    __builtin_amdgcn_s_setprio(0);
    if (T + 2 < NT) asm volatile("s_waitcnt vmcnt(6)" ::: "memory");
    else            asm volatile("s_waitcnt vmcnt(0)" ::: "memory");
    __builtin_amdgcn_s_barrier();
  }
  asm volatile("s_waitcnt vmcnt(0) lgkmcnt(0)" ::: "memory");
  __builtin_amdgcn_s_barrier();
}

// ---------------- GEMM1: h = gelu(Xd @ W1 + b1), bf16 out ----------------
// L2-window grid decode (verified round 9): 4Mx8N windows, col-major per XCD.
#define PITCH1 272  // shorts; 128 x 272 x 2B = 69,632 B (fits 128 KB)
__global__ __launch_bounds__(512, 2) void moe_gemm1(const short* __restrict__ Xd,
                                                    const short* __restrict__ W1bT,
                                                    const float* __restrict__ b1,
                                                    short* __restrict__ h,
                                                    const int* __restrict__ counts,
                                                    int m_base, int rows, int mch) {
  extern __shared__ short smem[];
  int bid = blockIdx.x;
  int xcd = bid & 7;
  int k = bid >> 3;           // 0 .. 2*NE*mch-1 (per-XCD sequence)
  int sub = k & 31;           // position in 4Mx8N window
  int win = k >> 5;           // per-XCD window index
  int Wm = NE * mch / 4;      // M-windows
  int g = win * 8 + xcd;      // global window id, col-major (wm fast, wn slow)
  int wm = g % Wm;
  int wn = g / Wm;            // 0 or 1
  int mlin = wm * 4 + (sub >> 3);
  int nn = wn * 8 + (sub & 7);
  int e = mlin / mch;
  int mm = mlin - e * mch;
  int cnt = counts[e]; if (cnt > CAP) cnt = CAP;
  int m0 = m_base + mm * 256;
  if (m0 >= cnt) return;
  int n0 = nn * 256;
  int t = threadIdx.x, l = t & 63, wid = t >> 6;
  int wr = wid >> 2, wc = wid & 3;
  const short* Ag = Xd + ((size_t)e * CAP + m0) * DIM;
  const short* Bg = W1bT + ((size_t)e * FFD + n0) * DIM;
  f32x4 acc[8][4];
#pragma unroll
  for (int mf = 0; mf < 8; mf++)
#pragma unroll
    for (int nf = 0; nf < 4; nf++) acc[mf][nf] = (f32x4){0.f, 0.f, 0.f, 0.f};
  mainloop256(Ag, DIM, Bg, DIM, DIM / 64, smem, acc, wr, wc, l, t);

  int l15 = l & 15, q4 = (l >> 4) * 4;
  float bias[4];
#pragma unroll
  for (int nf = 0; nf < 4; nf++)
    bias[nf] = b1[(size_t)e * FFD + n0 + wc * 64 + nf * 16 + l15];
#pragma unroll
  for (int half = 0; half < 2; half++) {
    if (wr == half) {
#pragma unroll
      for (int mf = 0; mf < 8; mf++)
#pragma unroll
        for (int nf = 0; nf < 4; nf++)
#pragma unroll
          for (int j = 0; j < 4; j++) {
            int lr = mf * 16 + q4 + j;
            int lc = wc * 64 + nf * 16 + l15;
            float v = acc[mf][nf][j] + bias[nf];
            smem[lr * PITCH1 + lc] = f2bf(gelu_tanh(v));
          }
    }
    asm volatile("s_waitcnt lgkmcnt(0)" ::: "memory");
    __builtin_amdgcn_s_barrier();
    int r = t >> 2, c0 = (t & 3) * 64;
    short* hrow = h + ((size_t)e * rows + (m0 - m_base) + half * 128 + r) * FFD + n0 + c0;
    const short* srow = smem + r * PITCH1 + c0;
#pragma unroll
    for (int i = 0; i < 8; i++)
      *(int4*)(hrow + i * 8) = *(const int4*)(srow + i * 8);
    asm volatile("s_waitcnt lgkmcnt(0)" ::: "memory");
    __builtin_amdgcn_s_barrier();
  }
}

// ---------------- GEMM2: out[token] = (h @ W2 + b2) * p_max, scatter ----------------
// Expert-pinned decode (round 10): XCD e owns expert e; 4Mx4N windows, M-major.
__global__ __launch_bounds__(512, 2) void moe_gemm2(const short* __restrict__ h,
                                                    const short* __restrict__ W2bT,
                                                    const float* __restrict__ b2,
                                                    const int* __restrict__ token_of_slot,
                                                    const float* __restrict__ pmax,
                                                    float* __restrict__ out,
                                                    const int* __restrict__ counts,
                                                    int m_base, int rows, int mch) {
  extern __shared__ short smem[];
  int bid = blockIdx.x;
  int e = bid & 7;            // expert == XCD
  int k = bid >> 3;           // 0 .. 4*mch-1 per XCD
  int sub = k & 15;           // 4M x 4N window
  int wm = k >> 4;            // 0 .. mch/4-1
  int nn = sub & 3;
  int mm = wm * 4 + (sub >> 2);
  int cnt = counts[e]; if (cnt > CAP) cnt = CAP;
  int m0 = m_base + mm * 256;
  if (m0 >= cnt) return;
  int n0 = nn * 256;
  int t = threadIdx.x, l = t & 63, wid = t >> 6;
  int wr = wid >> 2, wc = wid & 3;
  const short* Ag = h + ((size_t)e * rows + (m0 - m_base)) * FFD;
  const short* Bg = W2bT + ((size_t)e * DIM + n0) * FFD;
  f32x4 acc[8][4];
#pragma unroll
  for (int mf = 0; mf < 8; mf++)
#pragma unroll
    for (int nf = 0; nf < 4; nf++) acc[mf][nf] = (f32x4){0.f, 0.f, 0.f, 0.f};
  mainloop256(Ag, FFD, Bg, FFD, FFD / 64, smem, acc, wr, wc, l, t);

  float* ftile = (float*)smem;  // 128 x 256 f32 = 128 KB (exact fit)
  int l15 = l & 15, q4 = (l >> 4) * 4;
  float bias[4];
#pragma unroll
  for (int nf = 0; nf < 4; nf++)
    bias[nf] = b2[(size_t)e * DIM + n0 + wc * 64 + nf * 16 + l15];
#pragma unroll
  for (int half = 0; half < 2; half++) {
    if (wr == half) {
#pragma unroll
      for (int mf = 0; mf < 8; mf++)
#pragma unroll
        for (int nf = 0; nf < 4; nf++)
#pragma unroll
          for (int j = 0; j < 4; j++) {
            int lr = mf * 16 + q4 + j;
            int lc = wc * 64 + nf * 16 + l15;
            ftile[lr * 256 + lc] = acc[mf][nf][j] + bias[nf];
          }
    }
    asm volatile("s_waitcnt lgkmcnt(0)" ::: "memory");
    __builtin_amdgcn_s_barrier();
    int r = t >> 2, c0 = (t & 3) * 64;
    int slotrow = m0 + half * 128 + r;
    int tok = token_of_slot[e * CAP + slotrow];
    if (tok >= 0) {
      float f = pmax[tok];
      float* orow = out + (size_t)tok * DIM + n0 + c0;
      const float* srow = ftile + r * 256 + c0;
#pragma unroll
      for (int i = 0; i < 16; i++) {
        float4 v = *(const float4*)(srow + i * 4);
        v.x *= f; v.y *= f; v.z *= f; v.w *= f;
        *(float4*)(orow + i * 4) = v;
      }
    }
    asm volatile("s_waitcnt lgkmcnt(0)" ::: "memory");
    __builtin_amdgcn_s_barrier();
  }
}

// ---------------- dropped tokens: passthrough x ----------------
__global__ __launch_bounds__(256) void moe_fixup(const float* __restrict__ x,
                                                 const int* __restrict__ slot_of_token,
                                                 float* __restrict__ out) {
  int tok8 = blockIdx.x * 8 + (threadIdx.x >> 5);
  int lane32 = threadIdx.x & 31;
  if (slot_of_token[tok8] != NE * CAP) return;
#pragma unroll
  for (int i = 0; i < 8; i++) {
    int c = (i * 32 + lane32) * 4;
    float4 v = *(const float4*)(x + (size_t)tok8 * DIM + c);
    *(float4*)(out + (size_t)tok8 * DIM + c) = v;
  }
}

extern "C" void kernel_launch(void* const* d_in, const int* in_sizes, int n_in,
                              void* d_out, int out_size, void* d_ws, size_t ws_size,
                              hipStream_t stream) {
  (void)in_sizes; (void)n_in; (void)out_size;
  const float* x  = (const float*)d_in[0];
  const float* Wg = (const float*)d_in[1];
  const float* bg = (const float*)d_in[2];
  const float* W1 = (const float*)d_in[3];
  const float* b1 = (const float*)d_in[4];
  const float* W2 = (const float*)d_in[5];
  const float* b2 = (const float*)d_in[6];
  float* out = (float*)d_out;

  static bool attr_set = false;
  if (!attr_set) {
    hipFuncSetAttribute((const void*)moe_gemm1, hipFuncAttributeMaxDynamicSharedMemorySize, 131072);
    hipFuncSetAttribute((const void*)moe_gemm2, hipFuncAttributeMaxDynamicSharedMemorySize, 131072);
    attr_set = true;
  }

  char* p = (char*)d_ws;
  auto carve = [&](size_t bytes) -> char* {
    char* r = p;
    p += (bytes + 255) & ~(size_t)255;
    return r;
  };
  short* W1bT = (short*)carve((size_t)NE * DIM * FFD * 2);
  short* W2bT = (short*)carve((size_t)NE * DIM * FFD * 2);
  short* Xd   = (short*)carve((size_t)NE * CAP * DIM * 2);
  int* routes = (int*)carve((size_t)SEQ * 4);
  float* pmax = (float*)carve((size_t)SEQ * 4);
  int* slot_of_token = (int*)carve((size_t)SEQ * 4);
  int* token_of_slot = (int*)carve((size_t)(NE * CAP) * 4);
  int* counts = (int*)carve(256);
  size_t fixed = (size_t)(p - (char*)d_ws);

  // h rows per expert: multiple of 1024 so mch % 4 == 0 (window decodes)
  size_t avail = (ws_size > fixed + 4096) ? (ws_size - fixed - 4096) : 0;
  size_t per_row = (size_t)NE * FFD * 2;
  int rows = (int)(avail / per_row);
  rows &= ~1023;
  if (rows > CAP) rows = CAP;  // CAP = 5120 = 5*1024, mch = 20
  if (rows < 1024) rows = 1024;
  short* h = (short*)p;

  moe_router<<<SEQ / 4, 256, 0, stream>>>(x, Wg, bg, routes, pmax);
  moe_scan8<<<NE, 1024, 0, stream>>>(routes, slot_of_token, token_of_slot, counts);
  moe_gather<<<NE * CAP, 256, 0, stream>>>(x, token_of_slot, Xd);
  moe_convT2<<<dim3(4096, 1, 2 * NE), 256, 0, stream>>>(W1, W2, W1bT, W2bT);

  for (int r0 = 0; r0 < CAP; r0 += rows) {
    int cr = (CAP - r0 < rows) ? (CAP - r0) : rows;
    int mch = cr / 256;
    moe_gemm1<<<16 * NE * mch, 512, 131072, stream>>>(Xd, W1bT, b1, h, counts, r0, rows, mch);
    moe_gemm2<<<4 * NE * mch, 512, 131072, stream>>>(h, W2bT, b2, token_of_slot, pmax, out,
                                                     counts, r0, rows, mch);
  }
  moe_fixup<<<SEQ / 8, 256, 0, stream>>>(x, slot_of_token, out);
}

// Round 12
// 984.442 us; speedup vs baseline: 1.2827x; 1.0021x over previous
//
#include <hip/hip_runtime.h>
#include <stdint.h>

#define SEQ 32768
#define DIM 1024
#define FFD 4096
#define NE 8
#define CAP 5120

typedef __bf16 bf16x8 __attribute__((ext_vector_type(8)));
typedef float f32x4 __attribute__((ext_vector_type(4)));

__device__ __forceinline__ short f2bf(float f) {
  uint32_t u = __float_as_uint(f);
  uint32_t r = (u + 0x7fffu + ((u >> 16) & 1u)) >> 16;
  return (short)r;
}

__device__ __forceinline__ void async_copy16(const void* g, void* lds) {
  __builtin_amdgcn_global_load_lds((const __attribute__((address_space(1))) void*)g,
                                   (__attribute__((address_space(3))) void*)lds, 16, 0, 0);
}

// tanh-form gelu via __expf/__frcp_rn (verified round 7)
__device__ __forceinline__ float gelu_tanh(float v) {
  float u = v * v;
  float z = v * fmaf(0.07135371f, u, 1.5957691f);
  float E = __expf(z);
  float R = __frcp_rn(1.0f + E);
  return fmaf(-v, R, v);
}

// ---------------- router: logits in f64, argmax + p_max ----------------
__global__ __launch_bounds__(256) void moe_router(const float* __restrict__ x,
                                                  const float* __restrict__ Wg,
                                                  const float* __restrict__ bg,
                                                  int* __restrict__ routes,
                                                  float* __restrict__ pmax) {
  int token = blockIdx.x * 4 + (threadIdx.x >> 6);
  int lane = threadIdx.x & 63;
  const float* xr = x + (size_t)token * DIM;
  double acc[NE];
#pragma unroll
  for (int e = 0; e < NE; e++) acc[e] = 0.0;
#pragma unroll
  for (int i = 0; i < DIM / 64; i++) {
    int d = i * 64 + lane;
    double xv = (double)xr[d];
    const float* wr = Wg + (size_t)d * NE;
    float4 w0 = *(const float4*)(wr);
    float4 w1 = *(const float4*)(wr + 4);
    acc[0] += xv * (double)w0.x; acc[1] += xv * (double)w0.y;
    acc[2] += xv * (double)w0.z; acc[3] += xv * (double)w0.w;
    acc[4] += xv * (double)w1.x; acc[5] += xv * (double)w1.y;
    acc[6] += xv * (double)w1.z; acc[7] += xv * (double)w1.w;
  }
#pragma unroll
  for (int e = 0; e < NE; e++) {
#pragma unroll
    for (int off = 32; off >= 1; off >>= 1) acc[e] += __shfl_xor(acc[e], off);
  }
  if (lane == 0) {
    double l[NE];
#pragma unroll
    for (int e = 0; e < NE; e++) l[e] = acc[e] + (double)bg[e];
    int am = 0;
#pragma unroll
    for (int e = 1; e < NE; e++) if (l[e] > l[am]) am = e;
    double s = 0.0;
#pragma unroll
    for (int e = 0; e < NE; e++) s += exp(l[e] - l[am]);
    routes[token] = am;
    pmax[token] = (float)(1.0 / s);
  }
}

// ---------------- scan: per-expert FCFS positions, one block per expert --------------
__global__ __launch_bounds__(1024) void moe_scan8(const int* __restrict__ routes,
                                                  int* __restrict__ slot_of_token,
                                                  int* __restrict__ token_of_slot,
                                                  int* __restrict__ counts) {
  int E = blockIdx.x;
  __shared__ int wtot[16];
  __shared__ int woff[16];
  int t = threadIdx.x, lane = t & 63, w = t >> 6;
  for (int i = t; i < CAP; i += 1024) token_of_slot[E * CAP + i] = -1;
  int base = t * 32;
  int rloc[32];
  int cnt = 0;
#pragma unroll
  for (int i = 0; i < 32; i++) {
    int r = routes[base + i];
    rloc[i] = r;
    cnt += (r == E) ? 1 : 0;
  }
  int v = cnt;
#pragma unroll
  for (int off = 1; off < 64; off <<= 1) {
    int o = __shfl_up(v, off);
    if (lane >= off) v += o;
  }
  if (lane == 63) wtot[w] = v;
  __syncthreads();
  if (t == 0) {
    int run = 0;
    for (int ww = 0; ww < 16; ww++) { woff[ww] = run; run += wtot[ww]; }
    counts[E] = run;
  }
  __syncthreads();
  int pos = woff[w] + v - cnt;  // exclusive prefix for this thread
#pragma unroll
  for (int i = 0; i < 32; i++) {
    int tok = base + i;
    if (rloc[i] == E) {
      bool kept = pos < CAP;
      slot_of_token[tok] = kept ? E * CAP + pos : NE * CAP;
      if (kept) token_of_slot[E * CAP + pos] = tok;
      pos++;
    }
  }
}

// ------- merged prep: convT (both weights) + gather + fixup, one launch --------------
// All three depend only on scan (convT on nothing); merging overlaps them on the
// single in-order stream. bid ranges: [0,65536) convT, [65536,106496) gather,
// [106496,110592) fixup.
__global__ __launch_bounds__(256) void moe_prep(const float* __restrict__ x,
                                                const int* __restrict__ token_of_slot,
                                                const int* __restrict__ slot_of_token,
                                                short* __restrict__ Xd,
                                                const float* __restrict__ W1,
                                                const float* __restrict__ W2,
                                                short* __restrict__ WT1,
                                                short* __restrict__ WT2,
                                                float* __restrict__ out) {
  __shared__ float tile[32][33];
  int bid = blockIdx.x;
  int t = threadIdx.x;
  if (bid < 65536) {
    // ---- convT: f32 [E][K][N] -> bf16 [E][N][K]; float4 loads, short4 stores
    int z = bid >> 12;          // 0..15
    int idx = bid & 4095;
    const float* W;
    short* WT;
    int K, N;
    if (z < NE) { W = W1 + (size_t)z * DIM * FFD; WT = WT1 + (size_t)z * DIM * FFD; K = DIM; N = FFD; }
    else        { W = W2 + (size_t)(z - NE) * DIM * FFD; WT = WT2 + (size_t)(z - NE) * DIM * FFD; K = FFD; N = DIM; }
    int nb = N >> 5;
    int n0 = (idx % nb) * 32, k0 = (idx / nb) * 32;
    int r = t >> 3, c4 = (t & 7) * 4;
    float4 v = *(const float4*)(W + (size_t)(k0 + r) * N + n0 + c4);
    tile[r][c4] = v.x; tile[r][c4 + 1] = v.y; tile[r][c4 + 2] = v.z; tile[r][c4 + 3] = v.w;
    __syncthreads();
    int rn = t >> 3, k4 = (t & 7) * 4;
    short4 o;
    o.x = f2bf(tile[k4][rn]);
    o.y = f2bf(tile[k4 + 1][rn]);
    o.z = f2bf(tile[k4 + 2][rn]);
    o.w = f2bf(tile[k4 + 3][rn]);
    *(short4*)(WT + (size_t)(n0 + rn) * K + k0 + k4) = o;
  } else if (bid < 65536 + NE * CAP) {
    // ---- gather: dispatch buffer (bf16), zeros for empty slots
    int slot = bid - 65536;
    int tok = token_of_slot[slot];
    short* dst = Xd + (size_t)slot * DIM + t * 4;
    short4 v;
    if (tok < 0) {
      v.x = 0; v.y = 0; v.z = 0; v.w = 0;
    } else {
      float4 f = *(const float4*)(x + (size_t)tok * DIM + t * 4);
      v.x = f2bf(f.x); v.y = f2bf(f.y); v.z = f2bf(f.z); v.w = f2bf(f.w);
    }
    *(short4*)dst = v;
  } else {
    // ---- fixup: dropped tokens passthrough x
    int tok8 = (bid - (65536 + NE * CAP)) * 8 + (t >> 5);
    int lane32 = t & 31;
    if (slot_of_token[tok8] != NE * CAP) return;
#pragma unroll
    for (int i = 0; i < 8; i++) {
      int c = (i * 32 + lane32) * 4;
      float4 v = *(const float4*)(x + (size_t)tok8 * DIM + c);
      *(float4*)(out + (size_t)tok8 * DIM + c) = v;
    }
  }
}

// ================= 256x256 8-phase GEMM mainloop (A+B LDS, verified r4-r11) ============
// LDS bytes: A buf0 [0,32768) A buf1 [32768,65536) B buf0 [65536,98304) B buf1 [98304,131072)
// Swizzle: kbyte ^= (lrow&7)<<4 on global SOURCE (pre-swizzle) and on ds_read;
// gload_lds dest stays linear (rule #21).
__device__ __forceinline__ void mainloop256(const short* __restrict__ Ag, int lda,
                                            const short* __restrict__ Bg, int ldb,
                                            int NT, short* smem, f32x4 acc[8][4],
                                            int wr, int wc, int l, int t) {
  const int cb = ((t & 7) << 4) ^ (((t >> 3) & 7) << 4);
  const int rs = t >> 3;
  const int rb = ((rs >> 5) << 6) + (rs & 31);
  const size_t la2 = (size_t)lda * 2, lb2 = (size_t)ldb * 2;
  const char* pa0q0 = (const char*)Ag + (size_t)(rs)       * la2 + cb;
  const char* pa0q1 = (const char*)Ag + (size_t)(128 + rs) * la2 + cb;
  const char* pa1q0 = (const char*)Ag + (size_t)(64 + rs)  * la2 + cb;
  const char* pa1q1 = (const char*)Ag + (size_t)(192 + rs) * la2 + cb;
  const char* pb0q0 = (const char*)Bg + (size_t)(rb)       * lb2 + cb;
  const char* pb0q1 = (const char*)Bg + (size_t)(128 + rb) * lb2 + cb;
  const char* pb1q0 = (const char*)Bg + (size_t)(32 + rb)  * lb2 + cb;
  const char* pb1q1 = (const char*)Bg + (size_t)(160 + rb) * lb2 + cb;
  short* dA = smem + t * 8;
  short* dB = smem + 32768 + t * 8;

  auto STG = [&](const char*& p0, const char*& p1, short* d) {
    async_copy16(p0, d);
    async_copy16(p1, d + 4096);
    p0 += 128; p1 += 128;
  };

  STG(pa0q0, pa0q1, dA);
  STG(pb0q0, pb0q1, dB);
  STG(pa1q0, pa1q1, dA + 8192);
  STG(pb1q0, pb1q1, dB + 8192);
  STG(pa0q0, pa0q1, dA + 16384);
  STG(pb0q0, pb0q1, dB + 16384);
  STG(pa1q0, pa1q1, dA + 16384 + 8192);
  asm volatile("s_waitcnt vmcnt(6)" ::: "memory");
  __builtin_amdgcn_s_barrier();

  const int l15 = l & 15;
  const int kh16 = (l >> 4) << 4;
  const int swz = (l15 & 7) << 4;
  const char* paK0 = (const char*)smem + (wr * 64 + l15) * 128 + (kh16 ^ swz);
  const char* paK1 = (const char*)smem + (wr * 64 + l15) * 128 + ((64 + kh16) ^ swz);
  const char* pbK0 = (const char*)smem + 65536 + (wc * 32 + l15) * 128 + (kh16 ^ swz);
  const char* pbK1 = (const char*)smem + 65536 + (wc * 32 + l15) * 128 + ((64 + kh16) ^ swz);

  for (int T = 0; T < NT; T++) {
    const int selByte = (T & 1) << 15;
    const int selSh = (T & 1) << 14;
    const int selShN = ((T + 1) & 1) << 14;
    const char* pa0 = paK0 + selByte;
    const char* pa1 = paK1 + selByte;
    const char* pb0 = pbK0 + selByte;
    const char* pb1 = pbK1 + selByte;
    bf16x8 a[4][2], b0[2][2], b1[2][2];
#pragma unroll
    for (int mf = 0; mf < 4; mf++) {
      a[mf][0] = *(const bf16x8*)(pa0 + mf * 2048);
      a[mf][1] = *(const bf16x8*)(pa1 + mf * 2048);
    }
#pragma unroll
    for (int nf = 0; nf < 2; nf++) {
      b0[nf][0] = *(const bf16x8*)(pb0 + nf * 2048);
      b0[nf][1] = *(const bf16x8*)(pb1 + nf * 2048);
    }
    if (T + 1 < NT) STG(pb1q0, pb1q1, dB + 8192 + selShN);
    __builtin_amdgcn_s_barrier();
    __builtin_amdgcn_s_setprio(1);
#pragma unroll
    for (int mf = 0; mf < 4; mf++)
#pragma unroll
      for (int nf = 0; nf < 2; nf++)
#pragma unroll
        for (int kk = 0; kk < 2; kk++)
          acc[mf][nf] = __builtin_amdgcn_mfma_f32_16x16x32_bf16(a[mf][kk], b0[nf][kk], acc[mf][nf], 0, 0, 0);
    __builtin_amdgcn_s_setprio(0);
    __builtin_amdgcn_s_barrier();
#pragma unroll
    for (int nf = 0; nf < 2; nf++) {
      b1[nf][0] = *(const bf16x8*)(pb0 + 16384 + nf * 2048);
      b1[nf][1] = *(const bf16x8*)(pb1 + 16384 + nf * 2048);
    }
    if (T + 2 < NT) STG(pa0q0, pa0q1, dA + selSh);
    __builtin_amdgcn_s_barrier();
    __builtin_amdgcn_s_setprio(1);
#pragma unroll
    for (int mf = 0; mf < 4; mf++)
#pragma unroll
      for (int nf = 0; nf < 2; nf++)
#pragma unroll
        for (int kk = 0; kk < 2; kk++)
          acc[mf][nf + 2] = __builtin_amdgcn_mfma_f32_16x16x32_bf16(a[mf][kk], b1[nf][kk], acc[mf][nf + 2], 0, 0, 0);
    __builtin_amdgcn_s_setprio(0);
    __builtin_amdgcn_s_barrier();
#pragma unroll
    for (int mf = 0; mf < 4; mf++) {
      a[mf][0] = *(const bf16x8*)(pa0 + 16384 + mf * 2048);
      a[mf][1] = *(const bf16x8*)(pa1 + 16384 + mf * 2048);
    }
    if (T + 2 < NT) STG(pb0q0, pb0q1, dB + selSh);
    __builtin_amdgcn_s_barrier();
    __builtin_amdgcn_s_setprio(1);
#pragma unroll
    for (int mf = 0; mf < 4; mf++)
#pragma unroll
      for (int nf = 0; nf < 2; nf++)
#pragma unroll
        for (int kk = 0; kk < 2; kk++)
          acc[mf + 4][nf + 2] = __builtin_amdgcn_mfma_f32_16x16x32_bf16(a[mf][kk], b1[nf][kk], acc[mf + 4][nf + 2], 0, 0, 0);
    __builtin_amdgcn_s_setprio(0);
    __builtin_amdgcn_s_barrier();
    if (T + 2 < NT) STG(pa1q0, pa1q1, dA + 8192 + selSh);
    __builtin_amdgcn_s_barrier();
    __builtin_amdgcn_s_setprio(1);
#pragma unroll
    for (int mf = 0; mf < 4; mf++)
#pragma unroll
      for (int nf = 0; nf < 2; nf++)
#pragma unroll
        for (int kk = 0; kk < 2; kk++)
          acc[mf + 4][nf] = __builtin_amdgcn_mfma_f32_16x16x32_bf16(a[mf][kk], b0[nf][kk], acc[mf + 4][nf], 0, 0, 0);
    __builtin_amdgcn_s_setprio(0);
    if (T + 2 < NT) asm volatile("s_waitcnt vmcnt(6)" ::: "memory");
    else            asm volatile("s_waitcnt vmcnt(0)" ::: "memory");
    __builtin_amdgcn_s_barrier();
  }
  asm volatile("s_waitcnt vmcnt(0) lgkmcnt(0)" ::: "memory");
  __builtin_amdgcn_s_barrier();
}

// ---------------- GEMM1: h = gelu(Xd @ W1 + b1), bf16 out ----------------
// L2-window grid decode (verified round 9): 4Mx8N windows, col-major per XCD.
#define PITCH1 272  // shorts; 128 x 272 x 2B = 69,632 B (fits 128 KB)
__global__ __launch_bounds__(512, 2) void moe_gemm1(const short* __restrict__ Xd,
                                                    const short* __restrict__ W1bT,
                                                    const float* __restrict__ b1,
                                                    short* __restrict__ h,
                                                    const int* __restrict__ counts,
                                                    int m_base, int rows, int mch) {
  extern __shared__ short smem[];
  int bid = blockIdx.x;
  int xcd = bid & 7;
  int k = bid >> 3;           // 0 .. 2*NE*mch-1 (per-XCD sequence)
  int sub = k & 31;           // position in 4Mx8N window
  int win = k >> 5;           // per-XCD window index
  int Wm = NE * mch / 4;      // M-windows
  int g = win * 8 + xcd;      // global window id, col-major (wm fast, wn slow)
  int wm = g % Wm;
  int wn = g / Wm;            // 0 or 1
  int mlin = wm * 4 + (sub >> 3);
  int nn = wn * 8 + (sub & 7);
  int e = mlin / mch;
  int mm = mlin - e * mch;
  int cnt = counts[e]; if (cnt > CAP) cnt = CAP;
  int m0 = m_base + mm * 256;
  if (m0 >= cnt) return;
  int n0 = nn * 256;
  int t = threadIdx.x, l = t & 63, wid = t >> 6;
  int wr = wid >> 2, wc = wid & 3;
  const short* Ag = Xd + ((size_t)e * CAP + m0) * DIM;
  const short* Bg = W1bT + ((size_t)e * FFD + n0) * DIM;
  f32x4 acc[8][4];
#pragma unroll
  for (int mf = 0; mf < 8; mf++)
#pragma unroll
    for (int nf = 0; nf < 4; nf++) acc[mf][nf] = (f32x4){0.f, 0.f, 0.f, 0.f};
  mainloop256(Ag, DIM, Bg, DIM, DIM / 64, smem, acc, wr, wc, l, t);

  int l15 = l & 15, q4 = (l >> 4) * 4;
  float bias[4];
#pragma unroll
  for (int nf = 0; nf < 4; nf++)
    bias[nf] = b1[(size_t)e * FFD + n0 + wc * 64 + nf * 16 + l15];
#pragma unroll
  for (int half = 0; half < 2; half++) {
    if (wr == half) {
#pragma unroll
      for (int mf = 0; mf < 8; mf++)
#pragma unroll
        for (int nf = 0; nf < 4; nf++)
#pragma unroll
          for (int j = 0; j < 4; j++) {
            int lr = mf * 16 + q4 + j;
            int lc = wc * 64 + nf * 16 + l15;
            float v = acc[mf][nf][j] + bias[nf];
            smem[lr * PITCH1 + lc] = f2bf(gelu_tanh(v));
          }
    }
    asm volatile("s_waitcnt lgkmcnt(0)" ::: "memory");
    __builtin_amdgcn_s_barrier();
    int r = t >> 2, c0 = (t & 3) * 64;
    short* hrow = h + ((size_t)e * rows + (m0 - m_base) + half * 128 + r) * FFD + n0 + c0;
    const short* srow = smem + r * PITCH1 + c0;
#pragma unroll
    for (int i = 0; i < 8; i++)
      *(int4*)(hrow + i * 8) = *(const int4*)(srow + i * 8);
    asm volatile("s_waitcnt lgkmcnt(0)" ::: "memory");
    __builtin_amdgcn_s_barrier();
  }
}

// ---------------- GEMM2: out[token] = (h @ W2 + b2) * p_max, scatter ----------------
// Expert-pinned decode (round 10): XCD e owns expert e; 4Mx4N windows, M-major.
__global__ __launch_bounds__(512, 2) void moe_gemm2(const short* __restrict__ h,
                                                    const short* __restrict__ W2bT,
                                                    const float* __restrict__ b2,
                                                    const int* __restrict__ token_of_slot,
                                                    const float* __restrict__ pmax,
                                                    float* __restrict__ out,
                                                    const int* __restrict__ counts,
                                                    int m_base, int rows, int mch) {
  extern __shared__ short smem[];
  int bid = blockIdx.x;
  int e = bid & 7;            // expert == XCD
  int k = bid >> 3;           // 0 .. 4*mch-1 per XCD
  int sub = k & 15;           // 4M x 4N window
  int wm = k >> 4;            // 0 .. mch/4-1
  int nn = sub & 3;
  int mm = wm * 4 + (sub >> 2);
  int cnt = counts[e]; if (cnt > CAP) cnt = CAP;
  int m0 = m_base + mm * 256;
  if (m0 >= cnt) return;
  int n0 = nn * 256;
  int t = threadIdx.x, l = t & 63, wid = t >> 6;
  int wr = wid >> 2, wc = wid & 3;
  const short* Ag = h + ((size_t)e * rows + (m0 - m_base)) * FFD;
  const short* Bg = W2bT + ((size_t)e * DIM + n0) * FFD;
  f32x4 acc[8][4];
#pragma unroll
  for (int mf = 0; mf < 8; mf++)
#pragma unroll
    for (int nf = 0; nf < 4; nf++) acc[mf][nf] = (f32x4){0.f, 0.f, 0.f, 0.f};
  mainloop256(Ag, FFD, Bg, FFD, FFD / 64, smem, acc, wr, wc, l, t);

  float* ftile = (float*)smem;  // 128 x 256 f32 = 128 KB (exact fit)
  int l15 = l & 15, q4 = (l >> 4) * 4;
  float bias[4];
#pragma unroll
  for (int nf = 0; nf < 4; nf++)
    bias[nf] = b2[(size_t)e * DIM + n0 + wc * 64 + nf * 16 + l15];
#pragma unroll
  for (int half = 0; half < 2; half++) {
    if (wr == half) {
#pragma unroll
      for (int mf = 0; mf < 8; mf++)
#pragma unroll
        for (int nf = 0; nf < 4; nf++)
#pragma unroll
          for (int j = 0; j < 4; j++) {
            int lr = mf * 16 + q4 + j;
            int lc = wc * 64 + nf * 16 + l15;
            ftile[lr * 256 + lc] = acc[mf][nf][j] + bias[nf];
          }
    }
    asm volatile("s_waitcnt lgkmcnt(0)" ::: "memory");
    __builtin_amdgcn_s_barrier();
    int r = t >> 2, c0 = (t & 3) * 64;
    int slotrow = m0 + half * 128 + r;
    int tok = token_of_slot[e * CAP + slotrow];
    if (tok >= 0) {
      float f = pmax[tok];
      float* orow = out + (size_t)tok * DIM + n0 + c0;
      const float* srow = ftile + r * 256 + c0;
#pragma unroll
      for (int i = 0; i < 16; i++) {
        float4 v = *(const float4*)(srow + i * 4);
        v.x *= f; v.y *= f; v.z *= f; v.w *= f;
        *(float4*)(orow + i * 4) = v;
      }
    }
    asm volatile("s_waitcnt lgkmcnt(0)" ::: "memory");
    __builtin_amdgcn_s_barrier();
  }
}

extern "C" void kernel_launch(void* const* d_in, const int* in_sizes, int n_in,
                              void* d_out, int out_size, void* d_ws, size_t ws_size,
                              hipStream_t stream) {
  (void)in_sizes; (void)n_in; (void)out_size;
  const float* x  = (const float*)d_in[0];
  const float* Wg = (const float*)d_in[1];
  const float* bg = (const float*)d_in[2];
  const float* W1 = (const float*)d_in[3];
  const float* b1 = (const float*)d_in[4];
  const float* W2 = (const float*)d_in[5];
  const float* b2 = (const float*)d_in[6];
  float* out = (float*)d_out;

  static bool attr_set = false;
  if (!attr_set) {
    hipFuncSetAttribute((const void*)moe_gemm1, hipFuncAttributeMaxDynamicSharedMemorySize, 131072);
    hipFuncSetAttribute((const void*)moe_gemm2, hipFuncAttributeMaxDynamicSharedMemorySize, 131072);
    attr_set = true;
  }

  char* p = (char*)d_ws;
  auto carve = [&](size_t bytes) -> char* {
    char* r = p;
    p += (bytes + 255) & ~(size_t)255;
    return r;
  };
  short* W1bT = (short*)carve((size_t)NE * DIM * FFD * 2);
  short* W2bT = (short*)carve((size_t)NE * DIM * FFD * 2);
  short* Xd   = (short*)carve((size_t)NE * CAP * DIM * 2);
  int* routes = (int*)carve((size_t)SEQ * 4);
  float* pmax = (float*)carve((size_t)SEQ * 4);
  int* slot_of_token = (int*)carve((size_t)SEQ * 4);
  int* token_of_slot = (int*)carve((size_t)(NE * CAP) * 4);
  int* counts = (int*)carve(256);
  size_t fixed = (size_t)(p - (char*)d_ws);

  // h rows per expert: multiple of 1024 so mch % 4 == 0 (window decodes)
  size_t avail = (ws_size > fixed + 4096) ? (ws_size - fixed - 4096) : 0;
  size_t per_row = (size_t)NE * FFD * 2;
  int rows = (int)(avail / per_row);
  rows &= ~1023;
  if (rows > CAP) rows = CAP;  // CAP = 5120 = 5*1024, mch = 20
  if (rows < 1024) rows = 1024;
  short* h = (short*)p;

  moe_router<<<SEQ / 4, 256, 0, stream>>>(x, Wg, bg, routes, pmax);
  moe_scan8<<<NE, 1024, 0, stream>>>(routes, slot_of_token, token_of_slot, counts);
  // merged convT + gather + fixup (all depend only on scan; overlap on one stream)
  moe_prep<<<65536 + NE * CAP + SEQ / 8, 256, 0, stream>>>(
      x, token_of_slot, slot_of_token, Xd, W1, W2, W1bT, W2bT, out);

  for (int r0 = 0; r0 < CAP; r0 += rows) {
    int cr = (CAP - r0 < rows) ? (CAP - r0) : rows;
    int mch = cr / 256;
    moe_gemm1<<<16 * NE * mch, 512, 131072, stream>>>(Xd, W1bT, b1, h, counts, r0, rows, mch);
    moe_gemm2<<<4 * NE * mch, 512, 131072, stream>>>(h, W2bT, b2, token_of_slot, pmax, out,
                                                     counts, r0, rows, mch);
  }
}